// Round 1
// 1553.771 us; speedup vs baseline: 1.4527x; 1.4527x over previous
//
#include <hip/hip_runtime.h>
#include <hip/hip_bf16.h>
#include <math.h>

#define NHEADS 4
#define DMODEL 512
#define HQK 128
#define HV 256
#define BBATCH 8
#define SH 56
#define SWW 56
#define SEQN (SH*SWW)          // 3136
#define NTOK (BBATCH*SEQN)     // 25088
#define CH2 32
#define NC2 (SEQN/CH2)         // 98

typedef __bf16 bf16x8 __attribute__((ext_vector_type(8)));
typedef float  f32x4  __attribute__((ext_vector_type(4)));

__device__ __forceinline__ float silu_f(float v){ return v / (1.f + __expf(-v)); }

__device__ __forceinline__ float b2f(unsigned short u){
  union { unsigned int i; float f; } c; c.i = ((unsigned int)u) << 16; return c.f;
}
__device__ __forceinline__ unsigned short f2b(float f){
  union { float fv; unsigned int u; } c; c.fv = f;
  unsigned int r = c.u + 0x7FFFu + ((c.u >> 16) & 1u);   // RNE
  return (unsigned short)(r >> 16);
}
__device__ __forceinline__ float h2f(unsigned short u){
  _Float16 h; __builtin_memcpy(&h, &u, 2); return (float)h;
}
__device__ __forceinline__ unsigned short f2h(float f){
  _Float16 h = (_Float16)f; unsigned short u; __builtin_memcpy(&u, &h, 2); return u;
}
__device__ __forceinline__ float lsig16(float z){          // logsigmoid(z)/16
  float e = __expf(-fabsf(z));
  return (fminf(z, 0.f) - __logf(1.f + e)) * 0.0625f;
}
__device__ __forceinline__ void up8(uint4 v, unsigned short* o){
  o[0]=(unsigned short)v.x; o[1]=(unsigned short)(v.x>>16);
  o[2]=(unsigned short)v.y; o[3]=(unsigned short)(v.y>>16);
  o[4]=(unsigned short)v.z; o[5]=(unsigned short)(v.z>>16);
  o[6]=(unsigned short)v.w; o[7]=(unsigned short)(v.w>>16);
}
__device__ __forceinline__ uint4 pk8(const unsigned short* s){
  uint4 v;
  v.x = (unsigned)s[0] | ((unsigned)s[1]<<16);
  v.y = (unsigned)s[2] | ((unsigned)s[3]<<16);
  v.z = (unsigned)s[4] | ((unsigned)s[5]<<16);
  v.w = (unsigned)s[6] | ((unsigned)s[7]<<16);
  return v;
}

#define GLL16(gp, lp) __builtin_amdgcn_global_load_lds( \
    (const __attribute__((address_space(1))) unsigned int*)(gp), \
    (__attribute__((address_space(3))) unsigned int*)(lp), 16, 0, 0)

// ---------------- fp32 -> bf16 weight conversion ----------------
__global__ __launch_bounds__(256) void k_w2b(const float* __restrict__ w,
                                             unsigned short* __restrict__ o, int n){
  int i = (blockIdx.x*256 + threadIdx.x) << 2;
  if (i >= n) return;
  float4 v = *(const float4*)&w[i];
  ushort4 p;
  p.x = f2b(v.x); p.y = f2b(v.y); p.z = f2b(v.z); p.w = f2b(v.w);
  *(ushort4*)&o[i] = p;
}

// ---------------- Wc = gk_w2[1024,16] @ gk_w1[16,512] -> bf16 [1024][512] ----------------
__global__ __launch_bounds__(256) void k_wc(const float* __restrict__ w1,
                                            const float* __restrict__ w2,
                                            unsigned short* __restrict__ wc){
  int idx = blockIdx.x*256 + threadIdx.x;   // n*512 + k
  int n = idx >> 9, k = idx & 511;
  float acc = 0.f;
  #pragma unroll
  for (int r=0;r<16;++r) acc += w2[n*16+r]*w1[r*512+k];
  wc[idx] = f2b(acc);
}

// ---------------- conv 3x3 depthwise + SiLU -> xs (bf16) ----------------
__global__ __launch_bounds__(256) void k_conv_silu(const float* __restrict__ x,
                                                   const float* __restrict__ cw,
                                                   unsigned short* __restrict__ xs){
  int gid = blockIdx.x*256 + threadIdx.x;     // NTOK*128 threads
  int c4  = (gid & 127) << 2;
  int tok = gid >> 7;
  int b = tok / SEQN, sp = tok % SEQN;
  int hh = sp / SWW, ww = sp % SWW;
  float a0=0.f,a1=0.f,a2=0.f,a3=0.f;
  #pragma unroll
  for (int dh=-1; dh<=1; ++dh){
    int h2 = hh+dh; if (h2<0||h2>=SH) continue;
    #pragma unroll
    for (int dw=-1; dw<=1; ++dw){
      int w2 = ww+dw; if (w2<0||w2>=SWW) continue;
      const float4 xv = *(const float4*)&x[((size_t)(b*SEQN + h2*SWW + w2))*DMODEL + c4];
      int tap = (dh+1)*3 + (dw+1);
      a0 += xv.x * cw[(c4+0)*9 + tap];
      a1 += xv.y * cw[(c4+1)*9 + tap];
      a2 += xv.z * cw[(c4+2)*9 + tap];
      a3 += xv.w * cw[(c4+3)*9 + tap];
    }
  }
  ushort4 o;
  o.x = f2b(silu_f(a0)); o.y = f2b(silu_f(a1)); o.z = f2b(silu_f(a2)); o.w = f2b(silu_f(a3));
  *(ushort4*)&xs[(size_t)tok*DMODEL + c4] = o;
}

// ------- MFMA GEMM: C[M,N] = act(A_bf16[M,K] * W_bf16[N,K]^T + bias) -------
template<int ACT, int CBF>
__global__ __launch_bounds__(256) void k_gemm_mfma(const unsigned short* __restrict__ A,
                                                   const unsigned short* __restrict__ W,
                                                   const float* __restrict__ bias,
                                                   void* __restrict__ Cv,
                                                   int M, int N, int K){
  __shared__ unsigned short sA[128*32];
  __shared__ unsigned short sB[128*32];
  const int tid  = threadIdx.x;
  const int wave = tid >> 6, lane = tid & 63;
  const int lm = lane & 15, quad = lane >> 4;
  const int wm = wave & 1, wn = wave >> 1;
  const int m0 = blockIdx.y * 128, n0 = blockIdx.x * 128;

  const int r0 = tid >> 2,  c0 = (tid & 3) << 3;
  const int f1 = tid + 256;
  const int r1 = f1 >> 2,   c1 = (f1 & 3) << 3;

  f32x4 acc[4][4] = {};

  for (int kt = 0; kt < K; kt += 32){
    GLL16(&A[(size_t)(m0 + r0)*K + kt + c0], &sA[(size_t)tid*8]);
    GLL16(&A[(size_t)(m0 + r1)*K + kt + c1], &sA[(size_t)f1*8]);
    GLL16(&W[(size_t)(n0 + r0)*K + kt + c0], &sB[(size_t)tid*8]);
    GLL16(&W[(size_t)(n0 + r1)*K + kt + c1], &sB[(size_t)f1*8]);
    __syncthreads();
    bf16x8 af[4], bf[4];
    #pragma unroll
    for (int i=0;i<4;++i) af[i] = *(const bf16x8*)&sA[(wm*64 + i*16 + lm)*32 + quad*8];
    #pragma unroll
    for (int j=0;j<4;++j) bf[j] = *(const bf16x8*)&sB[(wn*64 + j*16 + lm)*32 + quad*8];
    #pragma unroll
    for (int i=0;i<4;++i)
      #pragma unroll
      for (int j=0;j<4;++j)
        acc[i][j] = __builtin_amdgcn_mfma_f32_16x16x32_bf16(af[i], bf[j], acc[i][j], 0, 0, 0);
    __syncthreads();
  }

  #pragma unroll
  for (int i=0;i<4;++i){
    #pragma unroll
    for (int r=0;r<4;++r){
      size_t m = (size_t)(m0 + wm*64 + i*16 + quad*4 + r);
      #pragma unroll
      for (int j=0;j<4;++j){
        int n = n0 + wn*64 + j*16 + lm;
        float v = acc[i][j][r];
        if (bias) v += bias[n];
        if (ACT==1) v = silu_f(v);
        if (CBF) ((unsigned short*)Cv)[m*(size_t)N + n] = f2b(v);
        else     ((float*)Cv)[m*(size_t)N + n] = v;
      }
    }
  }
}

// ---------------- prep: gates -> qe_f/ke_f in-place, delta fp16, eb tables ----------------
// grid = 784 blocks (b 0..7 x token-block cB 0..97), 256 threads; thread owns col pair (j, j+1).
__global__ __launch_bounds__(256) void k_prep(unsigned short* __restrict__ qkv,
                                              const unsigned short* __restrict__ z,
                                              unsigned short* __restrict__ dbuf,
                                              unsigned short* __restrict__ ebF,
                                              unsigned short* __restrict__ ebB){
  const int blk = blockIdx.x;
  const int bb = blk / NC2, cB = blk % NC2;
  const int j = threadIdx.x << 1;                 // 0..510
  const size_t base = (size_t)bb*SEQN + cB*CH2;
  const float sc = 0.08838834764831845f;          // 128^-0.5
  float bf0[CH2], bf1[CH2];
  float r0 = 0.f, r1 = 0.f;
  #pragma unroll
  for (int t=0;t<CH2;++t){
    size_t tok = base + t;
    unsigned int zz = *(const unsigned int*)&z[tok*1024 + j];
    r0 += lsig16(b2f((unsigned short)zz));
    r1 += lsig16(b2f((unsigned short)(zz>>16)));
    bf0[t] = r0; bf1[t] = r1;
    unsigned int qq = *(const unsigned int*)&qkv[tok*2048 + j];
    unsigned int kk = *(const unsigned int*)&qkv[tok*2048 + 512 + j];
    float e0 = __expf(r0),  e1 = __expf(r1);
    float n0 = __expf(-r0), n1 = __expf(-r1);
    unsigned int qo = (unsigned)f2b(b2f((unsigned short)qq)*e0*sc)
                    | ((unsigned)f2b(b2f((unsigned short)(qq>>16))*e1*sc) << 16);
    unsigned int ko = (unsigned)f2b(b2f((unsigned short)kk)*n0)
                    | ((unsigned)f2b(b2f((unsigned short)(kk>>16))*n1) << 16);
    *(unsigned int*)&qkv[tok*2048 + j] = qo;
    *(unsigned int*)&qkv[tok*2048 + 512 + j] = ko;
  }
  const int hh = j >> 7, d = j & 127;
  {
    int ef = ((bb*NHEADS + hh)*NC2 + cB)*HQK + d;
    *(unsigned int*)&ebF[ef] = (unsigned)f2h(__expf(bf0[CH2-1]))
                             | ((unsigned)f2h(__expf(bf1[CH2-1])) << 16);
  }
  r0 = 0.f; r1 = 0.f;
  #pragma unroll
  for (int t=CH2-1;t>=0;--t){
    size_t tok = base + t;
    unsigned int zz = *(const unsigned int*)&z[tok*1024 + 512 + j];
    r0 += lsig16(b2f((unsigned short)zz));
    r1 += lsig16(b2f((unsigned short)(zz>>16)));
    float d0 = r0 - bf0[t], d1 = r1 - bf1[t];
    *(unsigned int*)&dbuf[tok*512 + j] = (unsigned)f2h(d0) | ((unsigned)f2h(d1) << 16);
  }
  {
    int eb = ((bb*NHEADS + hh)*NC2 + (NC2-1-cB))*HQK + d;
    *(unsigned int*)&ebB[eb] = (unsigned)f2h(__expf(r0))
                             | ((unsigned)f2h(__expf(r1)) << 16);
  }
}

// ---------------- GLA state-only pass: DeltaS over a quarter (25/24 chunks) ----------------
// grid = 512: bx = q*256 + combo; combo = (vq | dir | h | b). Writes dS[bx][v64][d128] fp32.
__global__ __launch_bounds__(256) void k_gla_state(const unsigned short* __restrict__ qkvb,
                                                   const unsigned short* __restrict__ dbuf,
                                                   const unsigned short* __restrict__ ebFt,
                                                   const unsigned short* __restrict__ ebBt,
                                                   float* __restrict__ dS){
  __shared__ __align__(16) unsigned short sKeT[128*40];  // [d][t] stride 40
  __shared__ __align__(16) unsigned short sVT[64*40];    // [v][t]
  __shared__ float sEb[128];

  const int tid = threadIdx.x;
  const int bx = blockIdx.x;
  const int combo = bx & 255, q = bx >> 8;
  const int vq = combo & 3, dir = (combo>>2)&1, hh = (combo>>3)&3, bb = (combo>>5)&7;

  const int w = tid >> 6, lane = tid & 63;
  const int quad = lane >> 4, lm = lane & 15;
  const int ts = tid >> 3, o8 = tid & 7, d16 = o8 << 4;
  const int tl = tid & 31, vg = tid >> 5;

  const int kcol = 512 + hh*HQK, vcol = 1024 + hh*HV + vq*64;
  const int dcol = hh*HQK;
  const unsigned short* ebT = dir ? ebBt : ebFt;
  const int ebBase = (bb*NHEADS + hh)*NC2*HQK;
  const int c0 = q ? 25 : 0, c1 = q ? 49 : 25;

  f32x4 Sreg[8];
  #pragma unroll
  for (int i=0;i<8;++i){
    #pragma unroll
    for (int r=0;r<4;++r) Sreg[i][r] = 0.f;
  }

  for (int c = c0; c < c1; ++c){
    {
      int p = c*CH2 + ts;
      int n = dir ? (SEQN-1-p) : p;
      size_t tok = (size_t)bb*SEQN + n;
      uint4 k0 = *(const uint4*)&qkvb[tok*2048 + kcol + d16];
      uint4 k1 = *(const uint4*)&qkvb[tok*2048 + kcol + d16 + 8];
      unsigned short kb[16];
      up8(k0, kb); up8(k1, kb+8);
      if (dir){
        uint4 dd0 = *(const uint4*)&dbuf[tok*512 + dcol + d16];
        uint4 dd1 = *(const uint4*)&dbuf[tok*512 + dcol + d16 + 8];
        unsigned short dh[16];
        up8(dd0, dh); up8(dd1, dh+8);
        #pragma unroll
        for (int u=0;u<16;++u)
          kb[u] = f2b(b2f(kb[u]) * __expf(-h2f(dh[u])));
      }
      #pragma unroll
      for (int u=0;u<16;++u) sKeT[(d16+u)*40 + ts] = kb[u];
    }
    {
      int p = c*CH2 + tl;
      int n = dir ? (SEQN-1-p) : p;
      size_t tok = (size_t)bb*SEQN + n;
      uint4 uv = *(const uint4*)&qkvb[tok*2048 + vcol + vg*8];
      unsigned short su[8];
      up8(uv, su);
      #pragma unroll
      for (int u=0;u<8;++u) sVT[(vg*8+u)*40 + tl] = su[u];
    }
    if (tid < 128) sEb[tid] = h2f(ebT[ebBase + c*HQK + tid]);
    __syncthreads();
    bf16x8 vta = *(const bf16x8*)&sVT[(w*16+lm)*40 + quad*8];
    #pragma unroll
    for (int dt=0; dt<8; ++dt){
      bf16x8 kt = *(const bf16x8*)&sKeT[(dt*16+lm)*40 + quad*8];
      Sreg[dt] = __builtin_amdgcn_mfma_f32_16x16x32_bf16(vta, kt, Sreg[dt], 0, 0, 0);
      float eb = sEb[dt*16 + lm];
      #pragma unroll
      for (int r=0;r<4;++r) Sreg[dt][r] *= eb;
    }
    __syncthreads();
  }

  const size_t sbase = (size_t)bx * 8192;
  #pragma unroll
  for (int dt=0; dt<8; ++dt){
    #pragma unroll
    for (int r=0;r<4;++r)
      dS[sbase + (size_t)(w*16 + quad*4 + r)*128 + dt*16 + lm] = Sreg[dt][r];
  }
}

// ---------------- combine quarters: dS[combo] = D(q1) * dS_q0 + dS_q1 ----------------
// grid = 256 (combo), 256 threads. D(q1)[d] = prod_{c=25..48} eb_c[d].
__global__ __launch_bounds__(256) void k_gla_comb(float* __restrict__ dS,
                                                  const unsigned short* __restrict__ ebFt,
                                                  const unsigned short* __restrict__ ebBt){
  const int combo = blockIdx.x;
  const int dir = (combo>>2)&1, hh = (combo>>3)&3, bb = (combo>>5)&7;
  const unsigned short* ebT = dir ? ebBt : ebFt;
  const int ebBase = (bb*NHEADS + hh)*NC2*HQK;
  const int t = threadIdx.x;
  const int d0 = (t << 2) & 127;
  float D0=1.f, D1=1.f, D2=1.f, D3=1.f;
  for (int c=25; c<49; ++c){
    ushort4 ev = *(const ushort4*)&ebT[ebBase + c*HQK + d0];
    D0 *= h2f(ev.x); D1 *= h2f(ev.y); D2 *= h2f(ev.z); D3 *= h2f(ev.w);
  }
  const size_t b0 = (size_t)combo*8192, b1 = b0 + 256*8192;
  #pragma unroll
  for (int r=0;r<8;++r){
    int idx = r*1024 + (t<<2);
    float4 a  = *(const float4*)&dS[b0 + idx];
    float4 bs = *(const float4*)&dS[b1 + idx];
    float4 o;
    o.x = D0*a.x + bs.x; o.y = D1*a.y + bs.y;
    o.z = D2*a.z + bs.z; o.w = D3*a.w + bs.w;
    *(float4*)&dS[b0 + idx] = o;
  }
}

// ---------------- GLA chunked scan, half-sequence per block, CHUNK=32 ----------------
// grid = 512: bx = half*256 + combo; half 0: chunks 0..48 from S=0; half 1: 49..97 from S_init.
__global__ __launch_bounds__(256,1) void k_gla3(const unsigned short* __restrict__ qkvb,
                                                const unsigned short* __restrict__ dbuf,
                                                const unsigned short* __restrict__ ebFt,
                                                const unsigned short* __restrict__ ebBt,
                                                unsigned short* __restrict__ og,
                                                const float* __restrict__ dS){
  __shared__ __align__(16) unsigned short sQe[32*136];   // [t][d] stride 136
  __shared__ __align__(16) unsigned short sKe[32*136];   // [t][d]
  __shared__ __align__(16) unsigned short sKeT[128*40];  // [d][t] stride 40
  __shared__ __align__(16) unsigned short sVT[64*40];    // [v][t]
  __shared__ __align__(16) unsigned short sST[64*136];   // [v][d]  (bf16 mirror of S)
  __shared__ __align__(16) unsigned short sP[32*40];     // [t][s]
  __shared__ __align__(16) unsigned short sO[32*72];     // [t][v]
  __shared__ float sEb[128];

  const int tid = threadIdx.x;
  const int bx = blockIdx.x;
  const int combo = bx & 255, half = bx >> 8;
  const int vq = combo & 3, dir = (combo>>2)&1, hh = (combo>>3)&3, bb = (combo>>5)&7;

  const int w = tid >> 6, lane = tid & 63;
  const int quad = lane >> 4, lm = lane & 15;
  const int mt = w >> 1, nt = w & 1;
  const int ts = tid >> 3, o8 = tid & 7, d16 = o8 << 4;  // qe/ke stage mapping
  const int tl = tid & 31, vg = tid >> 5;                // v stage mapping

  const int qcol = hh*HQK, kcol = 512 + hh*HQK, vcol = 1024 + hh*HV + vq*64;
  const int dcol = hh*HQK;
  const unsigned short* ebT = dir ? ebBt : ebFt;
  const int ebBase = (bb*NHEADS + hh)*NC2*HQK;
  const size_t ogBase = ((size_t)((dir*BBATCH + bb)*NHEADS + hh)) * SEQN * HV;

  f32x4 Sreg[8];
  #pragma unroll
  for (int i=0;i<8;++i){
    #pragma unroll
    for (int r=0;r<4;++r) Sreg[i][r] = 0.f;
  }
  if (half){
    // load S_init (fp32) and mirror to bf16 sST
    const size_t sbase = (size_t)combo * 8192;
    #pragma unroll
    for (int dt=0; dt<8; ++dt){
      #pragma unroll
      for (int r=0;r<4;++r){
        float sv = dS[sbase + (size_t)(w*16 + quad*4 + r)*128 + dt*16 + lm];
        Sreg[dt][r] = sv;
        sST[(w*16 + quad*4 + r)*136 + dt*16 + lm] = f2b(sv);
      }
    }
  } else {
    for (int i = tid; i < 64*136; i += 256) sST[i] = 0;
  }
  __syncthreads();

  const int cBeg = half * 49, cEnd = cBeg + 49;
  for (int c = cBeg; c < cEnd; ++c){
    // ---- stage qe/ke (+backward gate fixup), v (transposed), eb ----
    {
      int p = c*CH2 + ts;
      int n = dir ? (SEQN-1-p) : p;
      size_t tok = (size_t)bb*SEQN + n;
      uint4 q0 = *(const uint4*)&qkvb[tok*2048 + qcol + d16];
      uint4 q1 = *(const uint4*)&qkvb[tok*2048 + qcol + d16 + 8];
      uint4 k0 = *(const uint4*)&qkvb[tok*2048 + kcol + d16];
      uint4 k1 = *(const uint4*)&qkvb[tok*2048 + kcol + d16 + 8];
      unsigned short kb[16];
      up8(k0, kb); up8(k1, kb+8);
      if (dir){
        uint4 dd0 = *(const uint4*)&dbuf[tok*512 + dcol + d16];
        uint4 dd1 = *(const uint4*)&dbuf[tok*512 + dcol + d16 + 8];
        unsigned short dh[16], qb[16];
        up8(dd0, dh); up8(dd1, dh+8);
        up8(q0, qb);  up8(q1, qb+8);
        #pragma unroll
        for (int u=0;u<16;++u){
          float du = h2f(dh[u]);
          qb[u] = f2b(b2f(qb[u]) * __expf(du));
          kb[u] = f2b(b2f(kb[u]) * __expf(-du));
        }
        q0 = pk8(qb); q1 = pk8(qb+8);
        k0 = pk8(kb); k1 = pk8(kb+8);
      }
      *(uint4*)&sQe[ts*136 + d16]     = q0;
      *(uint4*)&sQe[ts*136 + d16 + 8] = q1;
      *(uint4*)&sKe[ts*136 + d16]     = k0;
      *(uint4*)&sKe[ts*136 + d16 + 8] = k1;
      #pragma unroll
      for (int u=0;u<16;++u) sKeT[(d16+u)*40 + ts] = kb[u];
    }
    {
      int p = c*CH2 + tl;
      int n = dir ? (SEQN-1-p) : p;
      size_t tok = (size_t)bb*SEQN + n;
      uint4 uv = *(const uint4*)&qkvb[tok*2048 + vcol + vg*8];
      unsigned short su[8];
      up8(uv, su);
      #pragma unroll
      for (int u=0;u<8;++u) sVT[(vg*8+u)*40 + tl] = su[u];
    }
    if (tid < 128) sEb[tid] = h2f(ebT[ebBase + c*HQK + tid]);
    __syncthreads();
    // ---- phase1: A = Qe.Ke^T ; oT += ST.Qe^T ; mask -> sP ----
    bf16x8 qf[2][4];
    #pragma unroll
    for (int tt=0; tt<2; ++tt){
      #pragma unroll
      for (int ks=0; ks<4; ++ks)
        qf[tt][ks] = *(const bf16x8*)&sQe[(tt*16+lm)*136 + ks*32 + quad*8];
    }
    f32x4 a1;
    #pragma unroll
    for (int r=0;r<4;++r) a1[r] = 0.f;
    #pragma unroll
    for (int ks=0; ks<4; ++ks){
      bf16x8 kfr = *(const bf16x8*)&sKe[(nt*16+lm)*136 + ks*32 + quad*8];
      a1 = __builtin_amdgcn_mfma_f32_16x16x32_bf16(qf[mt][ks], kfr, a1, 0, 0, 0);
    }
    f32x4 ot[2];
    #pragma unroll
    for (int tt=0; tt<2; ++tt){
      #pragma unroll
      for (int r=0;r<4;++r) ot[tt][r] = 0.f;
    }
    #pragma unroll
    for (int ks=0; ks<4; ++ks){
      bf16x8 stf = *(const bf16x8*)&sST[(w*16+lm)*136 + ks*32 + quad*8];
      #pragma unroll
      for (int tt=0; tt<2; ++tt)
        ot[tt] = __builtin_amdgcn_mfma_f32_16x16x32_bf16(stf, qf[tt][ks], ot[tt], 0, 0, 0);
    }
    #pragma unroll
    for (int r=0;r<4;++r){
      int t = mt*16 + quad*4 + r, s = nt*16 + lm;
      sP[t*40 + s] = f2b((s <= t) ? a1[r] : 0.f);
    }
    __syncthreads();
    // ---- phase2: S' = eb*(S + VT.KeT^T) ; oT += VT.P^T ----
    bf16x8 vta = *(const bf16x8*)&sVT[(w*16+lm)*40 + quad*8];
    #pragma unroll
    for (int dt=0; dt<8; ++dt){
      bf16x8 kt = *(const bf16x8*)&sKeT[(dt*16+lm)*40 + quad*8];
      Sreg[dt] = __builtin_amdgcn_mfma_f32_16x16x32_bf16(vta, kt, Sreg[dt], 0, 0, 0);
      float eb = sEb[dt*16 + lm];
      #pragma unroll
      for (int r=0;r<4;++r){
        float sv = Sreg[dt][r] * eb;
        Sreg[dt][r] = sv;
        sST[(w*16 + quad*4 + r)*136 + dt*16 + lm] = f2b(sv);
      }
    }
    #pragma unroll
    for (int tt=0; tt<2; ++tt){
      bf16x8 pf = *(const bf16x8*)&sP[(tt*16+lm)*40 + quad*8];
      ot[tt] = __builtin_amdgcn_mfma_f32_16x16x32_bf16(vta, pf, ot[tt], 0, 0, 0);
      #pragma unroll
      for (int r=0;r<4;++r)
        sO[(tt*16+lm)*72 + w*16 + quad*4 + r] = f2b(ot[tt][r]);
    }
    __syncthreads();
    // ---- coalesced o store ----
    {
      int p = c*CH2 + ts;
      int n = dir ? (SEQN-1-p) : p;
      uint4 pk = *(const uint4*)&sO[ts*72 + (o8<<3)];
      *(uint4*)&og[ogBase + (size_t)n*HV + vq*64 + (o8<<3)] = pk;
    }
  } // chunks
}

// ---------------- rmsnorm(f)+rmsnorm(b), gate with silu(g) ----------------
__global__ __launch_bounds__(256) void k_gate(const unsigned short* __restrict__ og,
                                              const unsigned short* __restrict__ g,
                                              const float* __restrict__ gnw,
                                              const float* __restrict__ lnw,
                                              unsigned short* __restrict__ y){
  int tok = blockIdx.x;
  int bb = tok / SEQN, n = tok % SEQN;
  int hh = threadIdx.x >> 6, l = threadIdx.x & 63;
  int j4 = l << 2;
  size_t basef = ((size_t)((0*BBATCH+bb)*NHEADS+hh))*SEQN*HV + (size_t)n*HV + j4;
  size_t baseb = ((size_t)((1*BBATCH+bb)*NHEADS+hh))*SEQN*HV + (size_t)n*HV + j4;
  ushort4 ofu = *(const ushort4*)&og[basef];
  ushort4 obu = *(const ushort4*)&og[baseb];
  float of0=b2f(ofu.x), of1=b2f(ofu.y), of2=b2f(ofu.z), of3=b2f(ofu.w);
  float ob0=b2f(obu.x), ob1=b2f(obu.y), ob2=b2f(obu.z), ob3=b2f(obu.w);
  float ssf = of0*of0 + of1*of1 + of2*of2 + of3*of3;
  float ssb = ob0*ob0 + ob1*ob1 + ob2*ob2 + ob3*ob3;
  #pragma unroll
  for (int m=32;m>=1;m>>=1){ ssf += __shfl_xor(ssf,m,64); ssb += __shfl_xor(ssb,m,64); }
  float rf = rsqrtf(ssf*(1.f/HV) + 1e-5f);
  float rb = rsqrtf(ssb*(1.f/HV) + 1e-5f);
  float4 gn = *(const float4*)&gnw[j4];
  float4 ln = *(const float4*)&lnw[j4];
  ushort4 gvu = *(const ushort4*)&g[(size_t)tok*1024 + hh*HV + j4];  // silu already applied
  float g0=b2f(gvu.x), g1=b2f(gvu.y), g2=b2f(gvu.z), g3=b2f(gvu.w);
  ushort4 out;
  out.x = f2b(g0*(of0*rf*gn.x + ob0*rb*ln.x));
  out.y = f2b(g1*(of1*rf*gn.y + ob1*rb*ln.y));
  out.z = f2b(g2*(of2*rf*gn.z + ob2*rb*ln.z));
  out.w = f2b(g3*(of3*rf*gn.w + ob3*rb*ln.w));
  *(ushort4*)&y[(size_t)tok*1024 + hh*HV + j4] = out;
}

extern "C" void kernel_launch(void* const* d_in, const int* in_sizes, int n_in,
                              void* d_out, int out_size, void* d_ws, size_t ws_size,
                              hipStream_t stream){
  (void)in_sizes; (void)n_in; (void)out_size;
  const float* x    = (const float*)d_in[0];
  const float* cw   = (const float*)d_in[1];
  const float* qkvw = (const float*)d_in[2];
  const float* gkw1 = (const float*)d_in[3];
  const float* gkw2 = (const float*)d_in[4];
  const float* gkb2 = (const float*)d_in[5];
  const float* gw   = (const float*)d_in[6];
  const float* gb   = (const float*)d_in[7];
  const float* gnw  = (const float*)d_in[8];
  const float* lnw  = (const float*)d_in[9];
  const float* ow   = (const float*)d_in[10];

  // Workspace layout (bytes), total 232,816,640 (proven budget):
  //   qkv  bf16 [25088,2048]  @ 0           (103 MB) — prep overwrites q/k; first half reused as y
  //   g    bf16 [25088,1024]  @ 51380224    (51.4 MB, written AFTER gla; qkv q/k/v dead by then? no —
  //        g lives in qkv region's second half, written after k_gla3 when qkv is dead)
  //   og   bf16 [2,8,4,3136,256] @ 102760448 (103 MB)
  //        pre-scan overlays: zbuf @ +25690112 (51.4 MB), wqb @ +77070336 (2 MB), wc @ +80216064 (1 MB)
  //        wob @ +0 after k_gate.
  //   dbuf fp16 [25088,512]   @ 205520896   (25.7 MB)
  //   ebF  fp16 [8,4,98,128]  @ 231211008   (0.8 MB)
  //   ebB  fp16 [8,4,98,128]  @ 232013824   (0.8 MB)
  // d_out (51.4 MB) scratch until final GEMM:
  //   xs  bf16 [25088,512] @ 0 (25.7 MB)  — survives until g-GEMM (after gla)
  //   dS  fp32 [2,256,64,128] @ 25690112 (16.8 MB) — quarter states / S_init
  //   wgb bf16 [1024,512] @ 42467328 (1 MB)
  if (ws_size < 232816640u) return;
  char* wsb = (char*)d_ws;
  char* dob = (char*)d_out;
  unsigned short* qkv  = (unsigned short*)(wsb + 0);
  unsigned short* g    = (unsigned short*)(wsb + 51380224);
  unsigned short* og   = (unsigned short*)(wsb + 102760448);
  unsigned short* zbuf = (unsigned short*)(wsb + 102760448 + 25690112);
  unsigned short* wqb  = (unsigned short*)(wsb + 102760448 + 77070336);
  unsigned short* wc   = (unsigned short*)(wsb + 102760448 + 80216064);
  unsigned short* dbuf = (unsigned short*)(wsb + 205520896);
  unsigned short* ebF  = (unsigned short*)(wsb + 231211008);
  unsigned short* ebB  = (unsigned short*)(wsb + 232013824);
  unsigned short* xs   = (unsigned short*)(dob + 0);
  float*          dS   = (float*)(dob + 25690112);
  unsigned short* wgb  = (unsigned short*)(dob + 42467328);
  unsigned short* wob  = og;                         // after k_gate, og dead
  unsigned short* y    = qkv;                        // qkv dead after k_gla3
  float*          outp = (float*)d_out;

  k_conv_silu<<<NTOK*128/256, 256, 0, stream>>>(x, cw, xs);
  k_w2b<<<1024, 256, 0, stream>>>(qkvw, wqb, 2048*512);
  k_w2b<<<512,  256, 0, stream>>>(gw,   wgb, 1024*512);
  k_wc<<<2048, 256, 0, stream>>>(gkw1, gkw2, wc);
  k_gemm_mfma<0,1><<<dim3(16,196), 256, 0, stream>>>(xs, wqb, nullptr, qkv,  NTOK, 2048, 512);
  k_gemm_mfma<0,1><<<dim3(8,196),  256, 0, stream>>>(xs, wc,  gkb2,    zbuf, NTOK, 1024, 512);
  k_prep<<<BBATCH*NC2, 256, 0, stream>>>(qkv, zbuf, dbuf, ebF, ebB);
  k_gla_state<<<512, 256, 0, stream>>>(qkv, dbuf, ebF, ebB, dS);
  k_gla_comb<<<256, 256, 0, stream>>>(dS, ebF, ebB);
  k_gla3<<<512, 256, 0, stream>>>(qkv, dbuf, ebF, ebB, og, dS);
  k_gemm_mfma<1,1><<<dim3(8,196),  256, 0, stream>>>(xs, wgb, gb, g, NTOK, 1024, 512);
  k_gate<<<NTOK, 256, 0, stream>>>(og, g, gnw, lnw, y);
  k_w2b<<<512, 256, 0, stream>>>(ow, wob, 512*1024);
  k_gemm_mfma<0,0><<<dim3(4,196), 256, 0, stream>>>(y, wob, nullptr, outp, NTOK, 512, 1024);
}

// Round 2
// 1521.891 us; speedup vs baseline: 1.4831x; 1.0209x over previous
//
#include <hip/hip_runtime.h>
#include <hip/hip_bf16.h>
#include <math.h>

#define NHEADS 4
#define DMODEL 512
#define HQK 128
#define HV 256
#define BBATCH 8
#define SH 56
#define SWW 56
#define SEQN (SH*SWW)          // 3136
#define NTOK (BBATCH*SEQN)     // 25088
#define CH2 32
#define NC2 (SEQN/CH2)         // 98

typedef __bf16 bf16x8 __attribute__((ext_vector_type(8)));
typedef float  f32x4  __attribute__((ext_vector_type(4)));

__device__ __forceinline__ float silu_f(float v){ return v / (1.f + __expf(-v)); }

__device__ __forceinline__ float b2f(unsigned short u){
  union { unsigned int i; float f; } c; c.i = ((unsigned int)u) << 16; return c.f;
}
// f32 -> bf16 via hardware cvt (RNE); compiler fuses pairs into v_cvt_pk_bf16_f32
__device__ __forceinline__ unsigned short f2b(float f){
  __bf16 h = (__bf16)f;
  unsigned short u; __builtin_memcpy(&u, &h, 2); return u;
}
__device__ __forceinline__ float h2f(unsigned short u){
  _Float16 h; __builtin_memcpy(&h, &u, 2); return (float)h;
}
__device__ __forceinline__ unsigned short f2h(float f){
  _Float16 h = (_Float16)f; unsigned short u; __builtin_memcpy(&u, &h, 2); return u;
}
__device__ __forceinline__ float lsig16(float z){          // logsigmoid(z)/16
  float e = __expf(-fabsf(z));
  return (fminf(z, 0.f) - __logf(1.f + e)) * 0.0625f;
}
__device__ __forceinline__ void up8(uint4 v, unsigned short* o){
  o[0]=(unsigned short)v.x; o[1]=(unsigned short)(v.x>>16);
  o[2]=(unsigned short)v.y; o[3]=(unsigned short)(v.y>>16);
  o[4]=(unsigned short)v.z; o[5]=(unsigned short)(v.z>>16);
  o[6]=(unsigned short)v.w; o[7]=(unsigned short)(v.w>>16);
}
__device__ __forceinline__ uint4 pk8(const unsigned short* s){
  uint4 v;
  v.x = (unsigned)s[0] | ((unsigned)s[1]<<16);
  v.y = (unsigned)s[2] | ((unsigned)s[3]<<16);
  v.z = (unsigned)s[4] | ((unsigned)s[5]<<16);
  v.w = (unsigned)s[6] | ((unsigned)s[7]<<16);
  return v;
}

#define GLL16(gp, lp) __builtin_amdgcn_global_load_lds( \
    (const __attribute__((address_space(1))) unsigned int*)(gp), \
    (__attribute__((address_space(3))) unsigned int*)(lp), 16, 0, 0)

// ---------------- fp32 -> bf16 weight conversion ----------------
__global__ __launch_bounds__(256) void k_w2b(const float* __restrict__ w,
                                             unsigned short* __restrict__ o, int n){
  int i = (blockIdx.x*256 + threadIdx.x) << 2;
  if (i >= n) return;
  float4 v = *(const float4*)&w[i];
  ushort4 p;
  p.x = f2b(v.x); p.y = f2b(v.y); p.z = f2b(v.z); p.w = f2b(v.w);
  *(ushort4*)&o[i] = p;
}

// ---------------- Wc = gk_w2[1024,16] @ gk_w1[16,512] -> bf16 [1024][512] ----------------
__global__ __launch_bounds__(256) void k_wc(const float* __restrict__ w1,
                                            const float* __restrict__ w2,
                                            unsigned short* __restrict__ wc){
  int idx = blockIdx.x*256 + threadIdx.x;   // n*512 + k
  int n = idx >> 9, k = idx & 511;
  float acc = 0.f;
  #pragma unroll
  for (int r=0;r<16;++r) acc += w2[n*16+r]*w1[r*512+k];
  wc[idx] = f2b(acc);
}

// ---------------- conv 3x3 depthwise + SiLU -> xs (bf16) ----------------
__global__ __launch_bounds__(256) void k_conv_silu(const float* __restrict__ x,
                                                   const float* __restrict__ cw,
                                                   unsigned short* __restrict__ xs){
  int gid = blockIdx.x*256 + threadIdx.x;     // NTOK*128 threads
  int c4  = (gid & 127) << 2;
  int tok = gid >> 7;
  int b = tok / SEQN, sp = tok % SEQN;
  int hh = sp / SWW, ww = sp % SWW;
  float a0=0.f,a1=0.f,a2=0.f,a3=0.f;
  #pragma unroll
  for (int dh=-1; dh<=1; ++dh){
    int h2 = hh+dh; if (h2<0||h2>=SH) continue;
    #pragma unroll
    for (int dw=-1; dw<=1; ++dw){
      int w2 = ww+dw; if (w2<0||w2>=SWW) continue;
      const float4 xv = *(const float4*)&x[((size_t)(b*SEQN + h2*SWW + w2))*DMODEL + c4];
      int tap = (dh+1)*3 + (dw+1);
      a0 += xv.x * cw[(c4+0)*9 + tap];
      a1 += xv.y * cw[(c4+1)*9 + tap];
      a2 += xv.z * cw[(c4+2)*9 + tap];
      a3 += xv.w * cw[(c4+3)*9 + tap];
    }
  }
  ushort4 o;
  o.x = f2b(silu_f(a0)); o.y = f2b(silu_f(a1)); o.z = f2b(silu_f(a2)); o.w = f2b(silu_f(a3));
  *(ushort4*)&xs[(size_t)tok*DMODEL + c4] = o;
}

// ------- MFMA GEMM: C[M,N] = act(A_bf16[M,K] * W_bf16[N,K]^T + bias) -------
template<int ACT, int CBF>
__global__ __launch_bounds__(256) void k_gemm_mfma(const unsigned short* __restrict__ A,
                                                   const unsigned short* __restrict__ W,
                                                   const float* __restrict__ bias,
                                                   void* __restrict__ Cv,
                                                   int M, int N, int K){
  __shared__ unsigned short sA[128*32];
  __shared__ unsigned short sB[128*32];
  const int tid  = threadIdx.x;
  const int wave = tid >> 6, lane = tid & 63;
  const int lm = lane & 15, quad = lane >> 4;
  const int wm = wave & 1, wn = wave >> 1;
  const int m0 = blockIdx.y * 128, n0 = blockIdx.x * 128;

  const int r0 = tid >> 2,  c0 = (tid & 3) << 3;
  const int f1 = tid + 256;
  const int r1 = f1 >> 2,   c1 = (f1 & 3) << 3;

  f32x4 acc[4][4] = {};

  for (int kt = 0; kt < K; kt += 32){
    GLL16(&A[(size_t)(m0 + r0)*K + kt + c0], &sA[(size_t)tid*8]);
    GLL16(&A[(size_t)(m0 + r1)*K + kt + c1], &sA[(size_t)f1*8]);
    GLL16(&W[(size_t)(n0 + r0)*K + kt + c0], &sB[(size_t)tid*8]);
    GLL16(&W[(size_t)(n0 + r1)*K + kt + c1], &sB[(size_t)f1*8]);
    __syncthreads();
    bf16x8 af[4], bf[4];
    #pragma unroll
    for (int i=0;i<4;++i) af[i] = *(const bf16x8*)&sA[(wm*64 + i*16 + lm)*32 + quad*8];
    #pragma unroll
    for (int j=0;j<4;++j) bf[j] = *(const bf16x8*)&sB[(wn*64 + j*16 + lm)*32 + quad*8];
    #pragma unroll
    for (int i=0;i<4;++i)
      #pragma unroll
      for (int j=0;j<4;++j)
        acc[i][j] = __builtin_amdgcn_mfma_f32_16x16x32_bf16(af[i], bf[j], acc[i][j], 0, 0, 0);
    __syncthreads();
  }

  #pragma unroll
  for (int i=0;i<4;++i){
    #pragma unroll
    for (int r=0;r<4;++r){
      size_t m = (size_t)(m0 + wm*64 + i*16 + quad*4 + r);
      #pragma unroll
      for (int j=0;j<4;++j){
        int n = n0 + wn*64 + j*16 + lm;
        float v = acc[i][j][r];
        if (bias) v += bias[n];
        if (ACT==1) v = silu_f(v);
        if (CBF) ((unsigned short*)Cv)[m*(size_t)N + n] = f2b(v);
        else     ((float*)Cv)[m*(size_t)N + n] = v;
      }
    }
  }
}

// ---------------- prep: gates -> qe_f/ke_f in-place, exp(delta) fp16, eb tables ----------------
// grid = 784 blocks (b 0..7 x token-block cB 0..97), 256 threads; thread owns col pair (j, j+1).
// dbuf now stores exp(b_b - b_f) in fp16 (the dir=1 multiplicative fixup for q; k uses rcp).
__global__ __launch_bounds__(256) void k_prep(unsigned short* __restrict__ qkv,
                                              const unsigned short* __restrict__ z,
                                              unsigned short* __restrict__ dbuf,
                                              unsigned short* __restrict__ ebF,
                                              unsigned short* __restrict__ ebB){
  const int blk = blockIdx.x;
  const int bb = blk / NC2, cB = blk % NC2;
  const int j = threadIdx.x << 1;                 // 0..510
  const size_t base = (size_t)bb*SEQN + cB*CH2;
  const float sc = 0.08838834764831845f;          // 128^-0.5
  float bf0[CH2], bf1[CH2];
  float r0 = 0.f, r1 = 0.f;
  #pragma unroll
  for (int t=0;t<CH2;++t){
    size_t tok = base + t;
    unsigned int zz = *(const unsigned int*)&z[tok*1024 + j];
    r0 += lsig16(b2f((unsigned short)zz));
    r1 += lsig16(b2f((unsigned short)(zz>>16)));
    bf0[t] = r0; bf1[t] = r1;
    unsigned int qq = *(const unsigned int*)&qkv[tok*2048 + j];
    unsigned int kk = *(const unsigned int*)&qkv[tok*2048 + 512 + j];
    float e0 = __expf(r0),  e1 = __expf(r1);
    float n0 = __expf(-r0), n1 = __expf(-r1);
    unsigned int qo = (unsigned)f2b(b2f((unsigned short)qq)*e0*sc)
                    | ((unsigned)f2b(b2f((unsigned short)(qq>>16))*e1*sc) << 16);
    unsigned int ko = (unsigned)f2b(b2f((unsigned short)kk)*n0)
                    | ((unsigned)f2b(b2f((unsigned short)(kk>>16))*n1) << 16);
    *(unsigned int*)&qkv[tok*2048 + j] = qo;
    *(unsigned int*)&qkv[tok*2048 + 512 + j] = ko;
  }
  const int hh = j >> 7, d = j & 127;
  {
    int ef = ((bb*NHEADS + hh)*NC2 + cB)*HQK + d;
    *(unsigned int*)&ebF[ef] = (unsigned)f2h(__expf(bf0[CH2-1]))
                             | ((unsigned)f2h(__expf(bf1[CH2-1])) << 16);
  }
  r0 = 0.f; r1 = 0.f;
  #pragma unroll
  for (int t=CH2-1;t>=0;--t){
    size_t tok = base + t;
    unsigned int zz = *(const unsigned int*)&z[tok*1024 + 512 + j];
    r0 += lsig16(b2f((unsigned short)zz));
    r1 += lsig16(b2f((unsigned short)(zz>>16)));
    float d0 = r0 - bf0[t], d1 = r1 - bf1[t];
    *(unsigned int*)&dbuf[tok*512 + j] = (unsigned)f2h(__expf(d0))
                                       | ((unsigned)f2h(__expf(d1)) << 16);
  }
  {
    int eb = ((bb*NHEADS + hh)*NC2 + (NC2-1-cB))*HQK + d;
    *(unsigned int*)&ebB[eb] = (unsigned)f2h(__expf(r0))
                             | ((unsigned)f2h(__expf(r1)) << 16);
  }
}

// ---------------- GLA state-only pass: DeltaS over a segment (13/12 chunks) ----------------
// grid = 1024: bx = seg*256 + combo; seg 0..3 covers chunks [0,13),[13,25),[25,37),[37,49).
// Writes dSseg[bx][v64][d128] fp32 (parked in og region, dead until k_gla3).
__global__ __launch_bounds__(256) void k_gla_state(const unsigned short* __restrict__ qkvb,
                                                   const unsigned short* __restrict__ dbuf,
                                                   const unsigned short* __restrict__ ebFt,
                                                   const unsigned short* __restrict__ ebBt,
                                                   float* __restrict__ dSseg){
  __shared__ __align__(16) unsigned short sKeT[128*40];  // [d][t] stride 40
  __shared__ __align__(16) unsigned short sVT[64*40];    // [v][t]
  __shared__ float sEb[128];

  const int tid = threadIdx.x;
  const int bx = blockIdx.x;
  const int combo = bx & 255, seg = bx >> 8;
  const int vq = combo & 3, dir = (combo>>2)&1, hh = (combo>>3)&3, bb = (combo>>5)&7;

  const int w = tid >> 6, lane = tid & 63;
  const int quad = lane >> 4, lm = lane & 15;
  const int ts = tid >> 3, o8 = tid & 7, d16 = o8 << 4;
  const int tl = tid & 31, vg = tid >> 5;

  const int kcol = 512 + hh*HQK, vcol = 1024 + hh*HV + vq*64;
  const int dcol = hh*HQK;
  const unsigned short* ebT = dir ? ebBt : ebFt;
  const int ebBase = (bb*NHEADS + hh)*NC2*HQK;
  const int c0 = seg ? (13 + 12*(seg-1)) : 0;     // {0,13,25,37}
  const int c1 = 13 + 12*seg;                     // {13,25,37,49}

  f32x4 Sreg[8];
  #pragma unroll
  for (int i=0;i<8;++i){
    #pragma unroll
    for (int r=0;r<4;++r) Sreg[i][r] = 0.f;
  }

  for (int c = c0; c < c1; ++c){
    {
      int p = c*CH2 + ts;
      int n = dir ? (SEQN-1-p) : p;
      size_t tok = (size_t)bb*SEQN + n;
      uint4 k0 = *(const uint4*)&qkvb[tok*2048 + kcol + d16];
      uint4 k1 = *(const uint4*)&qkvb[tok*2048 + kcol + d16 + 8];
      unsigned short kb[16];
      up8(k0, kb); up8(k1, kb+8);
      if (dir){
        uint4 dd0 = *(const uint4*)&dbuf[tok*512 + dcol + d16];
        uint4 dd1 = *(const uint4*)&dbuf[tok*512 + dcol + d16 + 8];
        unsigned short eh[16];
        up8(dd0, eh); up8(dd1, eh+8);
        #pragma unroll
        for (int u=0;u<16;++u)
          kb[u] = f2b(b2f(kb[u]) * __builtin_amdgcn_rcpf(h2f(eh[u])));
      }
      #pragma unroll
      for (int u=0;u<16;++u) sKeT[(d16+u)*40 + ts] = kb[u];
    }
    {
      int p = c*CH2 + tl;
      int n = dir ? (SEQN-1-p) : p;
      size_t tok = (size_t)bb*SEQN + n;
      uint4 uv = *(const uint4*)&qkvb[tok*2048 + vcol + vg*8];
      unsigned short su[8];
      up8(uv, su);
      #pragma unroll
      for (int u=0;u<8;++u) sVT[(vg*8+u)*40 + tl] = su[u];
    }
    if (tid < 128) sEb[tid] = h2f(ebT[ebBase + c*HQK + tid]);
    __syncthreads();
    bf16x8 vta = *(const bf16x8*)&sVT[(w*16+lm)*40 + quad*8];
    #pragma unroll
    for (int dt=0; dt<8; ++dt){
      bf16x8 kt = *(const bf16x8*)&sKeT[(dt*16+lm)*40 + quad*8];
      Sreg[dt] = __builtin_amdgcn_mfma_f32_16x16x32_bf16(vta, kt, Sreg[dt], 0, 0, 0);
      float eb = sEb[dt*16 + lm];
      #pragma unroll
      for (int r=0;r<4;++r) Sreg[dt][r] *= eb;
    }
    __syncthreads();
  }

  const size_t sbase = (size_t)bx * 8192;
  #pragma unroll
  for (int dt=0; dt<8; ++dt){
    #pragma unroll
    for (int r=0;r<4;++r)
      dSseg[sbase + (size_t)(w*16 + quad*4 + r)*128 + dt*16 + lm] = Sreg[dt][r];
  }
}

// ---------------- combine segments: S_init(49) = DD*(DC*(DB*dA + dB) + dC) + dD ----------------
// grid = 256 (combo), 256 threads. D_X[d] = prod over segment X of eb_c[d].
__global__ __launch_bounds__(256) void k_gla_comb(const float* __restrict__ dSseg,
                                                  float* __restrict__ dSf,
                                                  const unsigned short* __restrict__ ebFt,
                                                  const unsigned short* __restrict__ ebBt){
  const int combo = blockIdx.x;
  const int dir = (combo>>2)&1, hh = (combo>>3)&3, bb = (combo>>5)&7;
  const unsigned short* ebT = dir ? ebBt : ebFt;
  const int ebBase = (bb*NHEADS + hh)*NC2*HQK;
  const int t = threadIdx.x;
  const int d0 = (t << 2) & 127;
  float DB[4]={1.f,1.f,1.f,1.f}, DC[4]={1.f,1.f,1.f,1.f}, DD[4]={1.f,1.f,1.f,1.f};
  for (int c=13; c<25; ++c){
    ushort4 ev = *(const ushort4*)&ebT[ebBase + c*HQK + d0];
    DB[0]*=h2f(ev.x); DB[1]*=h2f(ev.y); DB[2]*=h2f(ev.z); DB[3]*=h2f(ev.w);
  }
  for (int c=25; c<37; ++c){
    ushort4 ev = *(const ushort4*)&ebT[ebBase + c*HQK + d0];
    DC[0]*=h2f(ev.x); DC[1]*=h2f(ev.y); DC[2]*=h2f(ev.z); DC[3]*=h2f(ev.w);
  }
  for (int c=37; c<49; ++c){
    ushort4 ev = *(const ushort4*)&ebT[ebBase + c*HQK + d0];
    DD[0]*=h2f(ev.x); DD[1]*=h2f(ev.y); DD[2]*=h2f(ev.z); DD[3]*=h2f(ev.w);
  }
  const size_t bA = (size_t)combo*8192;
  const size_t SEG = (size_t)256*8192;
  #pragma unroll
  for (int r=0;r<8;++r){
    int idx = r*1024 + (t<<2);
    float4 a  = *(const float4*)&dSseg[bA + idx];
    float4 b4 = *(const float4*)&dSseg[bA + SEG + idx];
    float4 c4 = *(const float4*)&dSseg[bA + 2*SEG + idx];
    float4 d4 = *(const float4*)&dSseg[bA + 3*SEG + idx];
    float4 o;
    o.x = DD[0]*(DC[0]*(DB[0]*a.x + b4.x) + c4.x) + d4.x;
    o.y = DD[1]*(DC[1]*(DB[1]*a.y + b4.y) + c4.y) + d4.y;
    o.z = DD[2]*(DC[2]*(DB[2]*a.z + b4.z) + c4.z) + d4.z;
    o.w = DD[3]*(DC[3]*(DB[3]*a.w + b4.w) + c4.w) + d4.w;
    *(float4*)&dSf[bA + idx] = o;
  }
}

// ---------------- GLA chunked scan, half-sequence per block, CHUNK=32 ----------------
// grid = 512: bx = half*256 + combo; half 0: chunks 0..48 from S=0; half 1: 49..97 from S_init.
__global__ __launch_bounds__(256,1) void k_gla3(const unsigned short* __restrict__ qkvb,
                                                const unsigned short* __restrict__ dbuf,
                                                const unsigned short* __restrict__ ebFt,
                                                const unsigned short* __restrict__ ebBt,
                                                unsigned short* __restrict__ og,
                                                const float* __restrict__ dSf){
  __shared__ __align__(16) unsigned short sQe[32*136];   // [t][d] stride 136
  __shared__ __align__(16) unsigned short sKe[32*136];   // [t][d]
  __shared__ __align__(16) unsigned short sKeT[128*40];  // [d][t] stride 40
  __shared__ __align__(16) unsigned short sVT[64*40];    // [v][t]
  __shared__ __align__(16) unsigned short sST[64*136];   // [v][d]  (bf16 mirror of S)
  __shared__ __align__(16) unsigned short sP[32*40];     // [t][s]
  __shared__ __align__(16) unsigned short sO[32*72];     // [t][v]
  __shared__ float sEb[128];

  const int tid = threadIdx.x;
  const int bx = blockIdx.x;
  const int combo = bx & 255, half = bx >> 8;
  const int vq = combo & 3, dir = (combo>>2)&1, hh = (combo>>3)&3, bb = (combo>>5)&7;

  const int w = tid >> 6, lane = tid & 63;
  const int quad = lane >> 4, lm = lane & 15;
  const int mt = w >> 1, nt = w & 1;
  const int ts = tid >> 3, o8 = tid & 7, d16 = o8 << 4;  // qe/ke stage mapping
  const int tl = tid & 31, vg = tid >> 5;                // v stage mapping

  const int qcol = hh*HQK, kcol = 512 + hh*HQK, vcol = 1024 + hh*HV + vq*64;
  const int dcol = hh*HQK;
  const unsigned short* ebT = dir ? ebBt : ebFt;
  const int ebBase = (bb*NHEADS + hh)*NC2*HQK;
  const size_t ogBase = ((size_t)((dir*BBATCH + bb)*NHEADS + hh)) * SEQN * HV;

  f32x4 Sreg[8];
  #pragma unroll
  for (int i=0;i<8;++i){
    #pragma unroll
    for (int r=0;r<4;++r) Sreg[i][r] = 0.f;
  }
  if (half){
    // load S_init (fp32) and mirror to bf16 sST
    const size_t sbase = (size_t)combo * 8192;
    #pragma unroll
    for (int dt=0; dt<8; ++dt){
      #pragma unroll
      for (int r=0;r<4;++r){
        float sv = dSf[sbase + (size_t)(w*16 + quad*4 + r)*128 + dt*16 + lm];
        Sreg[dt][r] = sv;
        sST[(w*16 + quad*4 + r)*136 + dt*16 + lm] = f2b(sv);
      }
    }
  } else {
    for (int i = tid; i < 64*136; i += 256) sST[i] = 0;
  }
  __syncthreads();

  const int cBeg = half * 49, cEnd = cBeg + 49;
  for (int c = cBeg; c < cEnd; ++c){
    // ---- stage qe/ke (+backward gate fixup), v (transposed), eb ----
    {
      int p = c*CH2 + ts;
      int n = dir ? (SEQN-1-p) : p;
      size_t tok = (size_t)bb*SEQN + n;
      uint4 q0 = *(const uint4*)&qkvb[tok*2048 + qcol + d16];
      uint4 q1 = *(const uint4*)&qkvb[tok*2048 + qcol + d16 + 8];
      uint4 k0 = *(const uint4*)&qkvb[tok*2048 + kcol + d16];
      uint4 k1 = *(const uint4*)&qkvb[tok*2048 + kcol + d16 + 8];
      unsigned short kb[16];
      up8(k0, kb); up8(k1, kb+8);
      if (dir){
        uint4 dd0 = *(const uint4*)&dbuf[tok*512 + dcol + d16];
        uint4 dd1 = *(const uint4*)&dbuf[tok*512 + dcol + d16 + 8];
        unsigned short eh[16], qb[16];
        up8(dd0, eh); up8(dd1, eh+8);
        up8(q0, qb);  up8(q1, qb+8);
        #pragma unroll
        for (int u=0;u<16;++u){
          float e  = h2f(eh[u]);
          float ei = __builtin_amdgcn_rcpf(e);
          qb[u] = f2b(b2f(qb[u]) * e);
          kb[u] = f2b(b2f(kb[u]) * ei);
        }
        q0 = pk8(qb); q1 = pk8(qb+8);
        k0 = pk8(kb); k1 = pk8(kb+8);
      }
      *(uint4*)&sQe[ts*136 + d16]     = q0;
      *(uint4*)&sQe[ts*136 + d16 + 8] = q1;
      *(uint4*)&sKe[ts*136 + d16]     = k0;
      *(uint4*)&sKe[ts*136 + d16 + 8] = k1;
      #pragma unroll
      for (int u=0;u<16;++u) sKeT[(d16+u)*40 + ts] = kb[u];
    }
    {
      int p = c*CH2 + tl;
      int n = dir ? (SEQN-1-p) : p;
      size_t tok = (size_t)bb*SEQN + n;
      uint4 uv = *(const uint4*)&qkvb[tok*2048 + vcol + vg*8];
      unsigned short su[8];
      up8(uv, su);
      #pragma unroll
      for (int u=0;u<8;++u) sVT[(vg*8+u)*40 + tl] = su[u];
    }
    if (tid < 128) sEb[tid] = h2f(ebT[ebBase + c*HQK + tid]);
    __syncthreads();
    // ---- phase1: A = Qe.Ke^T ; oT += ST.Qe^T ; mask -> sP ----
    bf16x8 qf[2][4];
    #pragma unroll
    for (int tt=0; tt<2; ++tt){
      #pragma unroll
      for (int ks=0; ks<4; ++ks)
        qf[tt][ks] = *(const bf16x8*)&sQe[(tt*16+lm)*136 + ks*32 + quad*8];
    }
    f32x4 a1;
    #pragma unroll
    for (int r=0;r<4;++r) a1[r] = 0.f;
    #pragma unroll
    for (int ks=0; ks<4; ++ks){
      bf16x8 kfr = *(const bf16x8*)&sKe[(nt*16+lm)*136 + ks*32 + quad*8];
      a1 = __builtin_amdgcn_mfma_f32_16x16x32_bf16(qf[mt][ks], kfr, a1, 0, 0, 0);
    }
    f32x4 ot[2];
    #pragma unroll
    for (int tt=0; tt<2; ++tt){
      #pragma unroll
      for (int r=0;r<4;++r) ot[tt][r] = 0.f;
    }
    #pragma unroll
    for (int ks=0; ks<4; ++ks){
      bf16x8 stf = *(const bf16x8*)&sST[(w*16+lm)*136 + ks*32 + quad*8];
      #pragma unroll
      for (int tt=0; tt<2; ++tt)
        ot[tt] = __builtin_amdgcn_mfma_f32_16x16x32_bf16(stf, qf[tt][ks], ot[tt], 0, 0, 0);
    }
    #pragma unroll
    for (int r=0;r<4;++r){
      int t = mt*16 + quad*4 + r, s = nt*16 + lm;
      sP[t*40 + s] = f2b((s <= t) ? a1[r] : 0.f);
    }
    __syncthreads();
    // ---- phase2: S' = eb*(S + VT.KeT^T) ; oT += VT.P^T ----
    bf16x8 vta = *(const bf16x8*)&sVT[(w*16+lm)*40 + quad*8];
    #pragma unroll
    for (int dt=0; dt<8; ++dt){
      bf16x8 kt = *(const bf16x8*)&sKeT[(dt*16+lm)*40 + quad*8];
      Sreg[dt] = __builtin_amdgcn_mfma_f32_16x16x32_bf16(vta, kt, Sreg[dt], 0, 0, 0);
      float eb = sEb[dt*16 + lm];
      #pragma unroll
      for (int r=0;r<4;++r){
        float sv = Sreg[dt][r] * eb;
        Sreg[dt][r] = sv;
        sST[(w*16 + quad*4 + r)*136 + dt*16 + lm] = f2b(sv);
      }
    }
    #pragma unroll
    for (int tt=0; tt<2; ++tt){
      bf16x8 pf = *(const bf16x8*)&sP[(tt*16+lm)*40 + quad*8];
      ot[tt] = __builtin_amdgcn_mfma_f32_16x16x32_bf16(vta, pf, ot[tt], 0, 0, 0);
      #pragma unroll
      for (int r=0;r<4;++r)
        sO[(tt*16+lm)*72 + w*16 + quad*4 + r] = f2b(ot[tt][r]);
    }
    __syncthreads();
    // ---- coalesced o store ----
    {
      int p = c*CH2 + ts;
      int n = dir ? (SEQN-1-p) : p;
      uint4 pk = *(const uint4*)&sO[ts*72 + (o8<<3)];
      *(uint4*)&og[ogBase + (size_t)n*HV + vq*64 + (o8<<3)] = pk;
    }
  } // chunks
}

// ---------------- rmsnorm(f)+rmsnorm(b), gate with silu(g) ----------------
__global__ __launch_bounds__(256) void k_gate(const unsigned short* __restrict__ og,
                                              const unsigned short* __restrict__ g,
                                              const float* __restrict__ gnw,
                                              const float* __restrict__ lnw,
                                              unsigned short* __restrict__ y){
  int tok = blockIdx.x;
  int bb = tok / SEQN, n = tok % SEQN;
  int hh = threadIdx.x >> 6, l = threadIdx.x & 63;
  int j4 = l << 2;
  size_t basef = ((size_t)((0*BBATCH+bb)*NHEADS+hh))*SEQN*HV + (size_t)n*HV + j4;
  size_t baseb = ((size_t)((1*BBATCH+bb)*NHEADS+hh))*SEQN*HV + (size_t)n*HV + j4;
  ushort4 ofu = *(const ushort4*)&og[basef];
  ushort4 obu = *(const ushort4*)&og[baseb];
  float of0=b2f(ofu.x), of1=b2f(ofu.y), of2=b2f(ofu.z), of3=b2f(ofu.w);
  float ob0=b2f(obu.x), ob1=b2f(obu.y), ob2=b2f(obu.z), ob3=b2f(obu.w);
  float ssf = of0*of0 + of1*of1 + of2*of2 + of3*of3;
  float ssb = ob0*ob0 + ob1*ob1 + ob2*ob2 + ob3*ob3;
  #pragma unroll
  for (int m=32;m>=1;m>>=1){ ssf += __shfl_xor(ssf,m,64); ssb += __shfl_xor(ssb,m,64); }
  float rf = rsqrtf(ssf*(1.f/HV) + 1e-5f);
  float rb = rsqrtf(ssb*(1.f/HV) + 1e-5f);
  float4 gn = *(const float4*)&gnw[j4];
  float4 ln = *(const float4*)&lnw[j4];
  ushort4 gvu = *(const ushort4*)&g[(size_t)tok*1024 + hh*HV + j4];  // silu already applied
  float g0=b2f(gvu.x), g1=b2f(gvu.y), g2=b2f(gvu.z), g3=b2f(gvu.w);
  ushort4 out;
  out.x = f2b(g0*(of0*rf*gn.x + ob0*rb*ln.x));
  out.y = f2b(g1*(of1*rf*gn.y + ob1*rb*ln.y));
  out.z = f2b(g2*(of2*rf*gn.z + ob2*rb*ln.z));
  out.w = f2b(g3*(of3*rf*gn.w + ob3*rb*ln.w));
  *(ushort4*)&y[(size_t)tok*1024 + hh*HV + j4] = out;
}

extern "C" void kernel_launch(void* const* d_in, const int* in_sizes, int n_in,
                              void* d_out, int out_size, void* d_ws, size_t ws_size,
                              hipStream_t stream){
  (void)in_sizes; (void)n_in; (void)out_size;
  const float* x    = (const float*)d_in[0];
  const float* cw   = (const float*)d_in[1];
  const float* qkvw = (const float*)d_in[2];
  const float* gkw1 = (const float*)d_in[3];
  const float* gkw2 = (const float*)d_in[4];
  const float* gkb2 = (const float*)d_in[5];
  const float* gw   = (const float*)d_in[6];
  const float* gb   = (const float*)d_in[7];
  const float* gnw  = (const float*)d_in[8];
  const float* lnw  = (const float*)d_in[9];
  const float* ow   = (const float*)d_in[10];

  // Workspace layout (bytes), total 232,816,640 (proven budget):
  //   qkv  bf16 [25088,2048]  @ 0           (103 MB) — prep overwrites q/k; reused as y (first
  //        51.4MB) + g (second 51.4MB) after k_gla3 when qkv is dead
  //   og   bf16 [2,8,4,3136,256] @ 102760448 (103 MB)
  //        pre-gla3 overlays: dSseg fp32 [4,256,64,128] @ +0 (33.6 MB, written by gla_state,
  //        consumed by comb), zbuf @ +25690112 (51.4 MB, dead after prep — gla_state runs after),
  //        wqb @ +77070336 (2 MB), wc @ +80216064 (1 MB); wob @ +0 after k_gate.
  //   dbuf fp16 exp(delta) [25088,512] @ 205520896 (25.7 MB)
  //   ebF  fp16 [8,4,98,128]  @ 231211008   (0.8 MB)
  //   ebB  fp16 [8,4,98,128]  @ 232013824   (0.8 MB)
  // d_out (51.4 MB) scratch until final GEMM:
  //   xs  bf16 [25088,512] @ 0 (25.7 MB) — survives until g-GEMM (after gla)
  //   dSf fp32 [256,64,128] @ 25690112 (8.4 MB) — combined S_init for half-1
  //   wgb bf16 [1024,512] @ 42467328 (1 MB)
  if (ws_size < 232816640u) return;
  char* wsb = (char*)d_ws;
  char* dob = (char*)d_out;
  unsigned short* qkv  = (unsigned short*)(wsb + 0);
  unsigned short* g    = (unsigned short*)(wsb + 51380224);
  unsigned short* og   = (unsigned short*)(wsb + 102760448);
  float*          dSseg= (float*)(wsb + 102760448);
  unsigned short* zbuf = (unsigned short*)(wsb + 102760448 + 25690112);
  unsigned short* wqb  = (unsigned short*)(wsb + 102760448 + 77070336);
  unsigned short* wc   = (unsigned short*)(wsb + 102760448 + 80216064);
  unsigned short* dbuf = (unsigned short*)(wsb + 205520896);
  unsigned short* ebF  = (unsigned short*)(wsb + 231211008);
  unsigned short* ebB  = (unsigned short*)(wsb + 232013824);
  unsigned short* xs   = (unsigned short*)(dob + 0);
  float*          dSf  = (float*)(dob + 25690112);
  unsigned short* wgb  = (unsigned short*)(dob + 42467328);
  unsigned short* wob  = og;                         // after k_gate, og dead
  unsigned short* y    = qkv;                        // qkv dead after k_gla3
  float*          outp = (float*)d_out;

  k_conv_silu<<<NTOK*128/256, 256, 0, stream>>>(x, cw, xs);
  k_w2b<<<1024, 256, 0, stream>>>(qkvw, wqb, 2048*512);
  k_w2b<<<512,  256, 0, stream>>>(gw,   wgb, 1024*512);
  k_wc<<<2048, 256, 0, stream>>>(gkw1, gkw2, wc);
  k_gemm_mfma<0,1><<<dim3(16,196), 256, 0, stream>>>(xs, wqb, nullptr, qkv,  NTOK, 2048, 512);
  k_gemm_mfma<0,1><<<dim3(8,196),  256, 0, stream>>>(xs, wc,  gkb2,    zbuf, NTOK, 1024, 512);
  k_prep<<<BBATCH*NC2, 256, 0, stream>>>(qkv, zbuf, dbuf, ebF, ebB);
  k_gla_state<<<1024, 256, 0, stream>>>(qkv, dbuf, ebF, ebB, dSseg);
  k_gla_comb<<<256, 256, 0, stream>>>(dSseg, dSf, ebF, ebB);
  k_gla3<<<512, 256, 0, stream>>>(qkv, dbuf, ebF, ebB, og, dSf);
  k_gemm_mfma<1,1><<<dim3(8,196),  256, 0, stream>>>(xs, wgb, gb, g, NTOK, 1024, 512);
  k_gate<<<NTOK, 256, 0, stream>>>(og, g, gnw, lnw, y);
  k_w2b<<<512, 256, 0, stream>>>(ow, wob, 512*1024);
  k_gemm_mfma<0,0><<<dim3(4,196), 256, 0, stream>>>(y, wob, nullptr, outp, NTOK, 512, 1024);
}

// Round 4
// 1508.112 us; speedup vs baseline: 1.4966x; 1.0091x over previous
//
#include <hip/hip_runtime.h>
#include <hip/hip_bf16.h>
#include <math.h>

#define NHEADS 4
#define DMODEL 512
#define HQK 128
#define HV 256
#define BBATCH 8
#define SH 56
#define SWW 56
#define SEQN (SH*SWW)          // 3136
#define NTOK (BBATCH*SEQN)     // 25088
#define CH2 32
#define NC2 (SEQN/CH2)         // 98

typedef __bf16 bf16x8 __attribute__((ext_vector_type(8)));
typedef float  f32x4  __attribute__((ext_vector_type(4)));

__device__ __forceinline__ float silu_f(float v){ return v / (1.f + __expf(-v)); }

__device__ __forceinline__ float b2f(unsigned short u){
  union { unsigned int i; float f; } c; c.i = ((unsigned int)u) << 16; return c.f;
}
// f32 -> bf16 via hardware cvt (RNE); compiler fuses pairs into v_cvt_pk_bf16_f32
__device__ __forceinline__ unsigned short f2b(float f){
  __bf16 h = (__bf16)f;
  unsigned short u; __builtin_memcpy(&u, &h, 2); return u;
}
__device__ __forceinline__ float h2f(unsigned short u){
  _Float16 h; __builtin_memcpy(&h, &u, 2); return (float)h;
}
__device__ __forceinline__ unsigned short f2h(float f){
  _Float16 h = (_Float16)f; unsigned short u; __builtin_memcpy(&u, &h, 2); return u;
}
__device__ __forceinline__ float lsig16(float z){          // logsigmoid(z)/16
  float e = __expf(-fabsf(z));
  return (fminf(z, 0.f) - __logf(1.f + e)) * 0.0625f;
}
__device__ __forceinline__ void up8(uint4 v, unsigned short* o){
  o[0]=(unsigned short)v.x; o[1]=(unsigned short)(v.x>>16);
  o[2]=(unsigned short)v.y; o[3]=(unsigned short)(v.y>>16);
  o[4]=(unsigned short)v.z; o[5]=(unsigned short)(v.z>>16);
  o[6]=(unsigned short)v.w; o[7]=(unsigned short)(v.w>>16);
}
__device__ __forceinline__ uint4 pk8(const unsigned short* s){
  uint4 v;
  v.x = (unsigned)s[0] | ((unsigned)s[1]<<16);
  v.y = (unsigned)s[2] | ((unsigned)s[3]<<16);
  v.z = (unsigned)s[4] | ((unsigned)s[5]<<16);
  v.w = (unsigned)s[6] | ((unsigned)s[7]<<16);
  return v;
}

#define GLL16(gp, lp) __builtin_amdgcn_global_load_lds( \
    (const __attribute__((address_space(1))) unsigned int*)(gp), \
    (__attribute__((address_space(3))) unsigned int*)(lp), 16, 0, 0)

// ---------------- fp32 -> bf16 weight conversion ----------------
__global__ __launch_bounds__(256) void k_w2b(const float* __restrict__ w,
                                             unsigned short* __restrict__ o, int n){
  int i = (blockIdx.x*256 + threadIdx.x) << 2;
  if (i >= n) return;
  float4 v = *(const float4*)&w[i];
  ushort4 p;
  p.x = f2b(v.x); p.y = f2b(v.y); p.z = f2b(v.z); p.w = f2b(v.w);
  *(ushort4*)&o[i] = p;
}

// ---------------- Wc = gk_w2[1024,16] @ gk_w1[16,512] -> bf16 [1024][512] ----------------
__global__ __launch_bounds__(256) void k_wc(const float* __restrict__ w1,
                                            const float* __restrict__ w2,
                                            unsigned short* __restrict__ wc){
  int idx = blockIdx.x*256 + threadIdx.x;   // n*512 + k
  int n = idx >> 9, k = idx & 511;
  float acc = 0.f;
  #pragma unroll
  for (int r=0;r<16;++r) acc += w2[n*16+r]*w1[r*512+k];
  wc[idx] = f2b(acc);
}

// ---------------- conv 3x3 depthwise + SiLU -> xs (bf16) ----------------
__global__ __launch_bounds__(256) void k_conv_silu(const float* __restrict__ x,
                                                   const float* __restrict__ cw,
                                                   unsigned short* __restrict__ xs){
  int gid = blockIdx.x*256 + threadIdx.x;     // NTOK*128 threads
  int c4  = (gid & 127) << 2;
  int tok = gid >> 7;
  int b = tok / SEQN, sp = tok % SEQN;
  int hh = sp / SWW, ww = sp % SWW;
  float a0=0.f,a1=0.f,a2=0.f,a3=0.f;
  #pragma unroll
  for (int dh=-1; dh<=1; ++dh){
    int h2 = hh+dh; if (h2<0||h2>=SH) continue;
    #pragma unroll
    for (int dw=-1; dw<=1; ++dw){
      int w2 = ww+dw; if (w2<0||w2>=SWW) continue;
      const float4 xv = *(const float4*)&x[((size_t)(b*SEQN + h2*SWW + w2))*DMODEL + c4];
      int tap = (dh+1)*3 + (dw+1);
      a0 += xv.x * cw[(c4+0)*9 + tap];
      a1 += xv.y * cw[(c4+1)*9 + tap];
      a2 += xv.z * cw[(c4+2)*9 + tap];
      a3 += xv.w * cw[(c4+3)*9 + tap];
    }
  }
  ushort4 o;
  o.x = f2b(silu_f(a0)); o.y = f2b(silu_f(a1)); o.z = f2b(silu_f(a2)); o.w = f2b(silu_f(a3));
  *(ushort4*)&xs[(size_t)tok*DMODEL + c4] = o;
}

// ------- MFMA GEMM: C[M,N] = act(A_bf16[M,K] * W_bf16[N,K]^T + bias) -------
template<int ACT, int CBF>
__global__ __launch_bounds__(256) void k_gemm_mfma(const unsigned short* __restrict__ A,
                                                   const unsigned short* __restrict__ W,
                                                   const float* __restrict__ bias,
                                                   void* __restrict__ Cv,
                                                   int M, int N, int K){
  __shared__ unsigned short sA[128*32];
  __shared__ unsigned short sB[128*32];
  const int tid  = threadIdx.x;
  const int wave = tid >> 6, lane = tid & 63;
  const int lm = lane & 15, quad = lane >> 4;
  const int wm = wave & 1, wn = wave >> 1;
  const int m0 = blockIdx.y * 128, n0 = blockIdx.x * 128;

  const int r0 = tid >> 2,  c0 = (tid & 3) << 3;
  const int f1 = tid + 256;
  const int r1 = f1 >> 2,   c1 = (f1 & 3) << 3;

  f32x4 acc[4][4] = {};

  for (int kt = 0; kt < K; kt += 32){
    GLL16(&A[(size_t)(m0 + r0)*K + kt + c0], &sA[(size_t)tid*8]);
    GLL16(&A[(size_t)(m0 + r1)*K + kt + c1], &sA[(size_t)f1*8]);
    GLL16(&W[(size_t)(n0 + r0)*K + kt + c0], &sB[(size_t)tid*8]);
    GLL16(&W[(size_t)(n0 + r1)*K + kt + c1], &sB[(size_t)f1*8]);
    __syncthreads();
    bf16x8 af[4], bf[4];
    #pragma unroll
    for (int i=0;i<4;++i) af[i] = *(const bf16x8*)&sA[(wm*64 + i*16 + lm)*32 + quad*8];
    #pragma unroll
    for (int j=0;j<4;++j) bf[j] = *(const bf16x8*)&sB[(wn*64 + j*16 + lm)*32 + quad*8];
    #pragma unroll
    for (int i=0;i<4;++i)
      #pragma unroll
      for (int j=0;j<4;++j)
        acc[i][j] = __builtin_amdgcn_mfma_f32_16x16x32_bf16(af[i], bf[j], acc[i][j], 0, 0, 0);
    __syncthreads();
  }

  #pragma unroll
  for (int i=0;i<4;++i){
    #pragma unroll
    for (int r=0;r<4;++r){
      size_t m = (size_t)(m0 + wm*64 + i*16 + quad*4 + r);
      #pragma unroll
      for (int j=0;j<4;++j){
        int n = n0 + wn*64 + j*16 + lm;
        float v = acc[i][j][r];
        if (bias) v += bias[n];
        if (ACT==1) v = silu_f(v);
        if (CBF) ((unsigned short*)Cv)[m*(size_t)N + n] = f2b(v);
        else     ((float*)Cv)[m*(size_t)N + n] = v;
      }
    }
  }
}

// ---------------- prep: gates -> qe_f/ke_f in-place, exp(delta) fp16, eb tables ----------------
__global__ __launch_bounds__(256) void k_prep(unsigned short* __restrict__ qkv,
                                              const unsigned short* __restrict__ z,
                                              unsigned short* __restrict__ dbuf,
                                              unsigned short* __restrict__ ebF,
                                              unsigned short* __restrict__ ebB){
  const int blk = blockIdx.x;
  const int bb = blk / NC2, cB = blk % NC2;
  const int j = threadIdx.x << 1;                 // 0..510
  const size_t base = (size_t)bb*SEQN + cB*CH2;
  const float sc = 0.08838834764831845f;          // 128^-0.5
  float bf0[CH2], bf1[CH2];
  float r0 = 0.f, r1 = 0.f;
  #pragma unroll
  for (int t=0;t<CH2;++t){
    size_t tok = base + t;
    unsigned int zz = *(const unsigned int*)&z[tok*1024 + j];
    r0 += lsig16(b2f((unsigned short)zz));
    r1 += lsig16(b2f((unsigned short)(zz>>16)));
    bf0[t] = r0; bf1[t] = r1;
    unsigned int qq = *(const unsigned int*)&qkv[tok*2048 + j];
    unsigned int kk = *(const unsigned int*)&qkv[tok*2048 + 512 + j];
    float e0 = __expf(r0),  e1 = __expf(r1);
    float n0 = __expf(-r0), n1 = __expf(-r1);
    unsigned int qo = (unsigned)f2b(b2f((unsigned short)qq)*e0*sc)
                    | ((unsigned)f2b(b2f((unsigned short)(qq>>16))*e1*sc) << 16);
    unsigned int ko = (unsigned)f2b(b2f((unsigned short)kk)*n0)
                    | ((unsigned)f2b(b2f((unsigned short)(kk>>16))*n1) << 16);
    *(unsigned int*)&qkv[tok*2048 + j] = qo;
    *(unsigned int*)&qkv[tok*2048 + 512 + j] = ko;
  }
  const int hh = j >> 7, d = j & 127;
  {
    int ef = ((bb*NHEADS + hh)*NC2 + cB)*HQK + d;
    *(unsigned int*)&ebF[ef] = (unsigned)f2h(__expf(bf0[CH2-1]))
                             | ((unsigned)f2h(__expf(bf1[CH2-1])) << 16);
  }
  r0 = 0.f; r1 = 0.f;
  #pragma unroll
  for (int t=CH2-1;t>=0;--t){
    size_t tok = base + t;
    unsigned int zz = *(const unsigned int*)&z[tok*1024 + 512 + j];
    r0 += lsig16(b2f((unsigned short)zz));
    r1 += lsig16(b2f((unsigned short)(zz>>16)));
    float d0 = r0 - bf0[t], d1 = r1 - bf1[t];
    *(unsigned int*)&dbuf[tok*512 + j] = (unsigned)f2h(__expf(d0))
                                       | ((unsigned)f2h(__expf(d1)) << 16);
  }
  {
    int eb = ((bb*NHEADS + hh)*NC2 + (NC2-1-cB))*HQK + d;
    *(unsigned int*)&ebB[eb] = (unsigned)f2h(__expf(r0))
                             | ((unsigned)f2h(__expf(r1)) << 16);
  }
}

// ---------------- GLA state-only pass: DeltaS over sub-segments of the first 66 chunks --------
// grid = 1024: bx = seg*256 + combo; seg 0..3 covers chunks [0,17),[17,33),[33,50),[50,66).
__global__ __launch_bounds__(256) void k_gla_state(const unsigned short* __restrict__ qkvb,
                                                   const unsigned short* __restrict__ dbuf,
                                                   const unsigned short* __restrict__ ebFt,
                                                   const unsigned short* __restrict__ ebBt,
                                                   float* __restrict__ dSseg){
  __shared__ __align__(16) unsigned short sKeT[128*40];  // [d][t] stride 40
  __shared__ __align__(16) unsigned short sVT[64*40];    // [v][t]
  __shared__ float sEb[128];

  const int tid = threadIdx.x;
  const int bx = blockIdx.x;
  const int combo = bx & 255, seg = bx >> 8;
  const int vq = combo & 3, dir = (combo>>2)&1, hh = (combo>>3)&3, bb = (combo>>5)&7;

  const int w = tid >> 6, lane = tid & 63;
  const int quad = lane >> 4, lm = lane & 15;
  const int ts = tid >> 3, o8 = tid & 7, d16 = o8 << 4;
  const int tl = tid & 31, vg = tid >> 5;

  const int kcol = 512 + hh*HQK, vcol = 1024 + hh*HV + vq*64;
  const int dcol = hh*HQK;
  const unsigned short* ebT = dir ? ebBt : ebFt;
  const int ebBase = (bb*NHEADS + hh)*NC2*HQK;
  const int c0 = (seg==0)?0:(seg==1)?17:(seg==2)?33:50;
  const int c1 = (seg==0)?17:(seg==1)?33:(seg==2)?50:66;

  f32x4 Sreg[8];
  #pragma unroll
  for (int i=0;i<8;++i){
    #pragma unroll
    for (int r=0;r<4;++r) Sreg[i][r] = 0.f;
  }

  for (int c = c0; c < c1; ++c){
    {
      int p = c*CH2 + ts;
      int n = dir ? (SEQN-1-p) : p;
      size_t tok = (size_t)bb*SEQN + n;
      uint4 k0 = *(const uint4*)&qkvb[tok*2048 + kcol + d16];
      uint4 k1 = *(const uint4*)&qkvb[tok*2048 + kcol + d16 + 8];
      unsigned short kb[16];
      up8(k0, kb); up8(k1, kb+8);
      if (dir){
        uint4 dd0 = *(const uint4*)&dbuf[tok*512 + dcol + d16];
        uint4 dd1 = *(const uint4*)&dbuf[tok*512 + dcol + d16 + 8];
        unsigned short eh[16];
        up8(dd0, eh); up8(dd1, eh+8);
        #pragma unroll
        for (int u=0;u<16;++u)
          kb[u] = f2b(b2f(kb[u]) * __builtin_amdgcn_rcpf(h2f(eh[u])));
      }
      #pragma unroll
      for (int u=0;u<16;++u) sKeT[(d16+u)*40 + ts] = kb[u];
    }
    {
      int p = c*CH2 + tl;
      int n = dir ? (SEQN-1-p) : p;
      size_t tok = (size_t)bb*SEQN + n;
      uint4 uv = *(const uint4*)&qkvb[tok*2048 + vcol + vg*8];
      unsigned short su[8];
      up8(uv, su);
      #pragma unroll
      for (int u=0;u<8;++u) sVT[(vg*8+u)*40 + tl] = su[u];
    }
    if (tid < 128) sEb[tid] = h2f(ebT[ebBase + c*HQK + tid]);
    __syncthreads();
    bf16x8 vta = *(const bf16x8*)&sVT[(w*16+lm)*40 + quad*8];
    #pragma unroll
    for (int dt=0; dt<8; ++dt){
      bf16x8 kt = *(const bf16x8*)&sKeT[(dt*16+lm)*40 + quad*8];
      Sreg[dt] = __builtin_amdgcn_mfma_f32_16x16x32_bf16(vta, kt, Sreg[dt], 0, 0, 0);
      float eb = sEb[dt*16 + lm];
      #pragma unroll
      for (int r=0;r<4;++r) Sreg[dt][r] *= eb;
    }
    __syncthreads();
  }

  const size_t sbase = (size_t)bx * 8192;
  #pragma unroll
  for (int dt=0; dt<8; ++dt){
    #pragma unroll
    for (int r=0;r<4;++r)
      dSseg[sbase + (size_t)(w*16 + quad*4 + r)*128 + dt*16 + lm] = Sreg[dt][r];
  }
}

// ---------------- combine sub-segments into S33 and S66 ----------------
// grid = 256 (combo), 256 threads.
// S33 = DB*dA + dB ; S66 = DD*(DC*S33 + dC) + dD
__global__ __launch_bounds__(256) void k_gla_comb(const float* __restrict__ dSseg,
                                                  float* __restrict__ dSf,
                                                  const unsigned short* __restrict__ ebFt,
                                                  const unsigned short* __restrict__ ebBt){
  const int combo = blockIdx.x;
  const int dir = (combo>>2)&1, hh = (combo>>3)&3, bb = (combo>>5)&7;
  const unsigned short* ebT = dir ? ebBt : ebFt;
  const int ebBase = (bb*NHEADS + hh)*NC2*HQK;
  const int t = threadIdx.x;
  const int d0 = (t << 2) & 127;
  float DB[4]={1.f,1.f,1.f,1.f}, DC[4]={1.f,1.f,1.f,1.f}, DD[4]={1.f,1.f,1.f,1.f};
  for (int c=17; c<33; ++c){
    ushort4 ev = *(const ushort4*)&ebT[ebBase + c*HQK + d0];
    DB[0]*=h2f(ev.x); DB[1]*=h2f(ev.y); DB[2]*=h2f(ev.z); DB[3]*=h2f(ev.w);
  }
  for (int c=33; c<50; ++c){
    ushort4 ev = *(const ushort4*)&ebT[ebBase + c*HQK + d0];
    DC[0]*=h2f(ev.x); DC[1]*=h2f(ev.y); DC[2]*=h2f(ev.z); DC[3]*=h2f(ev.w);
  }
  for (int c=50; c<66; ++c){
    ushort4 ev = *(const ushort4*)&ebT[ebBase + c*HQK + d0];
    DD[0]*=h2f(ev.x); DD[1]*=h2f(ev.y); DD[2]*=h2f(ev.z); DD[3]*=h2f(ev.w);
  }
  const size_t bA = (size_t)combo*8192;
  const size_t SEG = (size_t)256*8192;
  #pragma unroll
  for (int r=0;r<8;++r){
    int idx = r*1024 + (t<<2);
    float4 a  = *(const float4*)&dSseg[bA + idx];
    float4 b4 = *(const float4*)&dSseg[bA + SEG + idx];
    float4 c4 = *(const float4*)&dSseg[bA + 2*SEG + idx];
    float4 d4 = *(const float4*)&dSseg[bA + 3*SEG + idx];
    float4 s33, s66;
    s33.x = DB[0]*a.x + b4.x; s33.y = DB[1]*a.y + b4.y;
    s33.z = DB[2]*a.z + b4.z; s33.w = DB[3]*a.w + b4.w;
    s66.x = DD[0]*(DC[0]*s33.x + c4.x) + d4.x;
    s66.y = DD[1]*(DC[1]*s33.y + c4.y) + d4.y;
    s66.z = DD[2]*(DC[2]*s33.z + c4.z) + d4.z;
    s66.w = DD[3]*(DC[3]*s33.w + c4.w) + d4.w;
    *(float4*)&dSf[bA + idx] = s33;
    *(float4*)&dSf[SEG + bA + idx] = s66;
  }
}

// ---------------- GLA chunked scan, third-of-sequence per block, CHUNK=32 ----------------
// grid = 768: bx = seg*256 + combo; seg 0: [0,33) from 0; seg 1: [33,66) from S33; seg 2: [66,98) from S66.
// LDS = 53,248 B -> 3 blocks/CU.
__global__ __launch_bounds__(256,3) void k_gla3(const unsigned short* __restrict__ qkvb,
                                                const unsigned short* __restrict__ dbuf,
                                                const unsigned short* __restrict__ ebFt,
                                                const unsigned short* __restrict__ ebBt,
                                                unsigned short* __restrict__ og,
                                                const float* __restrict__ dSf){
  __shared__ __align__(16) unsigned short sQe[32*136];   // [t][d] stride 136
  __shared__ __align__(16) unsigned short sKe[32*136];   // [t][d]
  __shared__ __align__(16) unsigned short sKeT[128*40];  // [d][t] stride 40
  __shared__ __align__(16) unsigned short sVT[64*40];    // [v][t]
  __shared__ __align__(16) unsigned short sST[64*136];   // [v][d]  (bf16 mirror of S)
  __shared__ __align__(16) unsigned short sP[32*40];     // [t][s]
  __shared__ float sEb[128];

  const int tid = threadIdx.x;
  const int bx = blockIdx.x;
  const int combo = bx & 255, seg = bx >> 8;
  const int vq = combo & 3, dir = (combo>>2)&1, hh = (combo>>3)&3, bb = (combo>>5)&7;

  const int w = tid >> 6, lane = tid & 63;
  const int quad = lane >> 4, lm = lane & 15;
  const int mt = w >> 1, nt = w & 1;
  const int ts = tid >> 3, o8 = tid & 7, d16 = o8 << 4;  // qe/ke stage mapping
  const int tl = tid & 31, vg = tid >> 5;                // v stage mapping

  const int qcol = hh*HQK, kcol = 512 + hh*HQK, vcol = 1024 + hh*HV + vq*64;
  const int dcol = hh*HQK;
  const unsigned short* ebT = dir ? ebBt : ebFt;
  const int ebBase = (bb*NHEADS + hh)*NC2*HQK;
  const size_t ogBase = ((size_t)((dir*BBATCH + bb)*NHEADS + hh)) * SEQN * HV;

  f32x4 Sreg[8];
  #pragma unroll
  for (int i=0;i<8;++i){
    #pragma unroll
    for (int r=0;r<4;++r) Sreg[i][r] = 0.f;
  }
  if (seg){
    // load S_init (fp32) and mirror to bf16 sST
    const size_t sbase = ((size_t)(seg-1)*256 + combo) * 8192;
    #pragma unroll
    for (int dt=0; dt<8; ++dt){
      #pragma unroll
      for (int r=0;r<4;++r){
        float sv = dSf[sbase + (size_t)(w*16 + quad*4 + r)*128 + dt*16 + lm];
        Sreg[dt][r] = sv;
        sST[(w*16 + quad*4 + r)*136 + dt*16 + lm] = f2b(sv);
      }
    }
  } else {
    for (int i = tid; i < 64*136; i += 256) sST[i] = 0;
  }
  __syncthreads();

  const int cBeg = seg * 33;
  const int cEnd = (seg == 2) ? NC2 : (cBeg + 33);
  for (int c = cBeg; c < cEnd; ++c){
    // ---- stage qe/ke (+backward gate fixup), v (transposed), eb ----
    {
      int p = c*CH2 + ts;
      int n = dir ? (SEQN-1-p) : p;
      size_t tok = (size_t)bb*SEQN + n;
      uint4 q0 = *(const uint4*)&qkvb[tok*2048 + qcol + d16];
      uint4 q1 = *(const uint4*)&qkvb[tok*2048 + qcol + d16 + 8];
      uint4 k0 = *(const uint4*)&qkvb[tok*2048 + kcol + d16];
      uint4 k1 = *(const uint4*)&qkvb[tok*2048 + kcol + d16 + 8];
      unsigned short kb[16];
      up8(k0, kb); up8(k1, kb+8);
      if (dir){
        uint4 dd0 = *(const uint4*)&dbuf[tok*512 + dcol + d16];
        uint4 dd1 = *(const uint4*)&dbuf[tok*512 + dcol + d16 + 8];
        unsigned short eh[16], qb[16];
        up8(dd0, eh); up8(dd1, eh+8);
        up8(q0, qb);  up8(q1, qb+8);
        #pragma unroll
        for (int u=0;u<16;++u){
          float e  = h2f(eh[u]);
          float ei = __builtin_amdgcn_rcpf(e);
          qb[u] = f2b(b2f(qb[u]) * e);
          kb[u] = f2b(b2f(kb[u]) * ei);
        }
        q0 = pk8(qb); q1 = pk8(qb+8);
        k0 = pk8(kb); k1 = pk8(kb+8);
      }
      *(uint4*)&sQe[ts*136 + d16]     = q0;
      *(uint4*)&sQe[ts*136 + d16 + 8] = q1;
      *(uint4*)&sKe[ts*136 + d16]     = k0;
      *(uint4*)&sKe[ts*136 + d16 + 8] = k1;
      #pragma unroll
      for (int u=0;u<16;++u) sKeT[(d16+u)*40 + ts] = kb[u];
    }
    {
      int p = c*CH2 + tl;
      int n = dir ? (SEQN-1-p) : p;
      size_t tok = (size_t)bb*SEQN + n;
      uint4 uv = *(const uint4*)&qkvb[tok*2048 + vcol + vg*8];
      unsigned short su[8];
      up8(uv, su);
      #pragma unroll
      for (int u=0;u<8;++u) sVT[(vg*8+u)*40 + tl] = su[u];
    }
    if (tid < 128) sEb[tid] = h2f(ebT[ebBase + c*HQK + tid]);
    __syncthreads();
    // ---- phase1: A = Qe.Ke^T ; oT += ST.Qe^T ; mask -> sP ----
    bf16x8 qf[2][4];
    #pragma unroll
    for (int tt=0; tt<2; ++tt){
      #pragma unroll
      for (int ks=0; ks<4; ++ks)
        qf[tt][ks] = *(const bf16x8*)&sQe[(tt*16+lm)*136 + ks*32 + quad*8];
    }
    f32x4 a1;
    #pragma unroll
    for (int r=0;r<4;++r) a1[r] = 0.f;
    #pragma unroll
    for (int ks=0; ks<4; ++ks){
      bf16x8 kfr = *(const bf16x8*)&sKe[(nt*16+lm)*136 + ks*32 + quad*8];
      a1 = __builtin_amdgcn_mfma_f32_16x16x32_bf16(qf[mt][ks], kfr, a1, 0, 0, 0);
    }
    f32x4 ot[2];
    #pragma unroll
    for (int tt=0; tt<2; ++tt){
      #pragma unroll
      for (int r=0;r<4;++r) ot[tt][r] = 0.f;
    }
    #pragma unroll
    for (int ks=0; ks<4; ++ks){
      bf16x8 stf = *(const bf16x8*)&sST[(w*16+lm)*136 + ks*32 + quad*8];
      #pragma unroll
      for (int tt=0; tt<2; ++tt)
        ot[tt] = __builtin_amdgcn_mfma_f32_16x16x32_bf16(stf, qf[tt][ks], ot[tt], 0, 0, 0);
    }
    #pragma unroll
    for (int r=0;r<4;++r){
      int t = mt*16 + quad*4 + r, s = nt*16 + lm;
      sP[t*40 + s] = f2b((s <= t) ? a1[r] : 0.f);
    }
    __syncthreads();
    // ---- phase2: S' = eb*(S + VT.KeT^T) ; oT += VT.P^T ; direct o store ----
    bf16x8 vta = *(const bf16x8*)&sVT[(w*16+lm)*40 + quad*8];
    #pragma unroll
    for (int dt=0; dt<8; ++dt){
      bf16x8 kt = *(const bf16x8*)&sKeT[(dt*16+lm)*40 + quad*8];
      Sreg[dt] = __builtin_amdgcn_mfma_f32_16x16x32_bf16(vta, kt, Sreg[dt], 0, 0, 0);
      float eb = sEb[dt*16 + lm];
      #pragma unroll
      for (int r=0;r<4;++r){
        float sv = Sreg[dt][r] * eb;
        Sreg[dt][r] = sv;
        sST[(w*16 + quad*4 + r)*136 + dt*16 + lm] = f2b(sv);
      }
    }
    #pragma unroll
    for (int tt=0; tt<2; ++tt){
      bf16x8 pf = *(const bf16x8*)&sP[(tt*16+lm)*40 + quad*8];
      ot[tt] = __builtin_amdgcn_mfma_f32_16x16x32_bf16(vta, pf, ot[tt], 0, 0, 0);
      // direct store: o[t = tt*16+lm][v = w*16 + quad*4 + r], r=0..3 packed as 8B
      int p = c*CH2 + tt*16 + lm;
      int n = dir ? (SEQN-1-p) : p;
      ushort4 o4;
      o4.x = f2b(ot[tt][0]); o4.y = f2b(ot[tt][1]);
      o4.z = f2b(ot[tt][2]); o4.w = f2b(ot[tt][3]);
      *(ushort4*)&og[ogBase + (size_t)n*HV + vq*64 + w*16 + quad*4] = o4;
    }
    __syncthreads();
  } // chunks
}

// ---------------- rmsnorm(f)+rmsnorm(b), gate with silu(g) ----------------
__global__ __launch_bounds__(256) void k_gate(const unsigned short* __restrict__ og,
                                              const unsigned short* __restrict__ g,
                                              const float* __restrict__ gnw,
                                              const float* __restrict__ lnw,
                                              unsigned short* __restrict__ y){
  int tok = blockIdx.x;
  int bb = tok / SEQN, n = tok % SEQN;
  int hh = threadIdx.x >> 6, l = threadIdx.x & 63;
  int j4 = l << 2;
  size_t basef = ((size_t)((0*BBATCH+bb)*NHEADS+hh))*SEQN*HV + (size_t)n*HV + j4;
  size_t baseb = ((size_t)((1*BBATCH+bb)*NHEADS+hh))*SEQN*HV + (size_t)n*HV + j4;
  ushort4 ofu = *(const ushort4*)&og[basef];
  ushort4 obu = *(const ushort4*)&og[baseb];
  float of0=b2f(ofu.x), of1=b2f(ofu.y), of2=b2f(ofu.z), of3=b2f(ofu.w);
  float ob0=b2f(obu.x), ob1=b2f(obu.y), ob2=b2f(obu.z), ob3=b2f(obu.w);
  float ssf = of0*of0 + of1*of1 + of2*of2 + of3*of3;
  float ssb = ob0*ob0 + ob1*ob1 + ob2*ob2 + ob3*ob3;
  #pragma unroll
  for (int m=32;m>=1;m>>=1){ ssf += __shfl_xor(ssf,m,64); ssb += __shfl_xor(ssb,m,64); }
  float rf = rsqrtf(ssf*(1.f/HV) + 1e-5f);
  float rb = rsqrtf(ssb*(1.f/HV) + 1e-5f);
  float4 gn = *(const float4*)&gnw[j4];
  float4 ln = *(const float4*)&lnw[j4];
  ushort4 gvu = *(const ushort4*)&g[(size_t)tok*1024 + hh*HV + j4];  // silu already applied
  float g0=b2f(gvu.x), g1=b2f(gvu.y), g2=b2f(gvu.z), g3=b2f(gvu.w);
  ushort4 out;
  out.x = f2b(g0*(of0*rf*gn.x + ob0*rb*ln.x));
  out.y = f2b(g1*(of1*rf*gn.y + ob1*rb*ln.y));
  out.z = f2b(g2*(of2*rf*gn.z + ob2*rb*ln.z));
  out.w = f2b(g3*(of3*rf*gn.w + ob3*rb*ln.w));
  *(ushort4*)&y[(size_t)tok*1024 + hh*HV + j4] = out;
}

extern "C" void kernel_launch(void* const* d_in, const int* in_sizes, int n_in,
                              void* d_out, int out_size, void* d_ws, size_t ws_size,
                              hipStream_t stream){
  (void)in_sizes; (void)n_in; (void)out_size;
  const float* x    = (const float*)d_in[0];
  const float* cw   = (const float*)d_in[1];
  const float* qkvw = (const float*)d_in[2];
  const float* gkw1 = (const float*)d_in[3];
  const float* gkw2 = (const float*)d_in[4];
  const float* gkb2 = (const float*)d_in[5];
  const float* gw   = (const float*)d_in[6];
  const float* gb   = (const float*)d_in[7];
  const float* gnw  = (const float*)d_in[8];
  const float* lnw  = (const float*)d_in[9];
  const float* ow   = (const float*)d_in[10];

  // Workspace layout (bytes), total 232,816,640 (proven budget):
  //   qkv  bf16 [25088,2048]  @ 0           (103 MB) — prep overwrites q/k; reused as y (first
  //        51.4MB) + g (second 51.4MB) after k_gla3 when qkv is dead
  //   og   bf16 [2,8,4,3136,256] @ 102760448 (103 MB)
  //        pre-gla3 overlays: dSseg fp32 [4,256,64,128] @ +0 (33.6 MB, written by gla_state
  //        after zbuf is dead, consumed by comb), zbuf @ +25690112 (51.4 MB, dead after prep),
  //        wqb @ +77070336 (2 MB), wc @ +80216064 (1 MB); wob @ +0 after k_gate.
  //   dbuf fp16 exp(delta) [25088,512] @ 205520896 (25.7 MB)
  //   ebF  fp16 [8,4,98,128]  @ 231211008   (0.8 MB)
  //   ebB  fp16 [8,4,98,128]  @ 232013824   (0.8 MB)
  // d_out (51.4 MB) scratch until final GEMM:
  //   xs  bf16 [25088,512] @ 0 (25.7 MB) — survives until g-GEMM (after gla)
  //   dSf fp32 [2,256,64,128] @ 25690112 (16.8 MB) — S33/S66 for segs 1,2
  //   wgb bf16 [1024,512] @ 42467328 (1 MB)
  if (ws_size < 232816640u) return;
  char* wsb = (char*)d_ws;
  char* dob = (char*)d_out;
  unsigned short* qkv  = (unsigned short*)(wsb + 0);
  unsigned short* g    = (unsigned short*)(wsb + 51380224);
  unsigned short* og   = (unsigned short*)(wsb + 102760448);
  float*          dSseg= (float*)(wsb + 102760448);
  unsigned short* zbuf = (unsigned short*)(wsb + 102760448 + 25690112);
  unsigned short* wqb  = (unsigned short*)(wsb + 102760448 + 77070336);
  unsigned short* wc   = (unsigned short*)(wsb + 102760448 + 80216064);
  unsigned short* dbuf = (unsigned short*)(wsb + 205520896);
  unsigned short* ebF  = (unsigned short*)(wsb + 231211008);
  unsigned short* ebB  = (unsigned short*)(wsb + 232013824);
  unsigned short* xs   = (unsigned short*)(dob + 0);
  float*          dSf  = (float*)(dob + 25690112);
  unsigned short* wgb  = (unsigned short*)(dob + 42467328);
  unsigned short* wob  = og;                         // after k_gate, og dead
  unsigned short* y    = qkv;                        // qkv dead after k_gla3
  float*          outp = (float*)d_out;

  k_conv_silu<<<NTOK*128/256, 256, 0, stream>>>(x, cw, xs);
  k_w2b<<<1024, 256, 0, stream>>>(qkvw, wqb, 2048*512);
  k_w2b<<<512,  256, 0, stream>>>(gw,   wgb, 1024*512);
  k_wc<<<2048, 256, 0, stream>>>(gkw1, gkw2, wc);
  k_gemm_mfma<0,1><<<dim3(16,196), 256, 0, stream>>>(xs, wqb, nullptr, qkv,  NTOK, 2048, 512);
  k_gemm_mfma<0,1><<<dim3(8,196),  256, 0, stream>>>(xs, wc,  gkb2,    zbuf, NTOK, 1024, 512);
  k_prep<<<BBATCH*NC2, 256, 0, stream>>>(qkv, zbuf, dbuf, ebF, ebB);
  k_gla_state<<<1024, 256, 0, stream>>>(qkv, dbuf, ebF, ebB, dSseg);
  k_gla_comb<<<256, 256, 0, stream>>>(dSseg, dSf, ebF, ebB);
  k_gla3<<<768, 256, 0, stream>>>(qkv, dbuf, ebF, ebB, og, dSf);
  k_gemm_mfma<1,1><<<dim3(8,196),  256, 0, stream>>>(xs, wgb, gb, g, NTOK, 1024, 512);
  k_gate<<<NTOK, 256, 0, stream>>>(og, g, gnw, lnw, y);
  k_w2b<<<512, 256, 0, stream>>>(ow, wob, 512*1024);
  k_gemm_mfma<0,0><<<dim3(4,196), 256, 0, stream>>>(y, wob, nullptr, outp, NTOK, 512, 1024);
}